// Round 4
// baseline (515.764 us; speedup 1.0000x reference)
//
#include <hip/hip_runtime.h>
#include <cstdint>

typedef unsigned short u16;
typedef unsigned char u8;
typedef unsigned long long u64;
typedef __attribute__((ext_vector_type(8))) short bf16x8;
typedef __attribute__((ext_vector_type(4))) float f32x4;

__device__ __forceinline__ u16 f2b(float f){
  union { float f; uint32_t i; } v; v.f = f;
  uint32_t r = v.i + 0x7FFFu + ((v.i >> 16) & 1u);   // RNE
  return (u16)(r >> 16);
}
__device__ __forceinline__ float b2f(u16 u){
  union { uint32_t i; float f; } v; v.i = ((uint32_t)u) << 16; return v.f;
}
__device__ __forceinline__ float sigmoidf(float x){ return 1.0f / (1.0f + __expf(-x)); }

#define MFMA16(a,b,c) __builtin_amdgcn_mfma_f32_16x16x32_bf16(a,b,c,0,0,0)

// ---- K0: build wT (transposed, bf16 hi/lo split) of allw = concat(w0,w1),
// stored in BALLOT-PERMUTED k order: within each 1024-k block,
// kappa(j) = (j'>>8)*256 + (j'&3)*64 + ((j'>>2)&63), j' = j&1023.
// (GEMM sums over k; A-fragments built from ballot words use the same order.)
__global__ __launch_bounds__(256) void k_prep(
    const float* __restrict__ w0, const float* __restrict__ w1,
    u16* __restrict__ wThi, u16* __restrict__ wTlo){
  __shared__ float tile[64][65];
  int tid = threadIdx.x;
  int t = blockIdx.x;                       // 0..127
  int b = t >> 6, kt = t & 63;
  int k0 = kt * 64;
  const float* src = (k0 < 2048) ? (w0 + ((size_t)b*2048 + k0)*64)
                                 : (w1 + ((size_t)b*2048 + (k0 - 2048))*64);
  int r0 = tid >> 6, c = tid & 63;
  #pragma unroll
  for (int it = 0; it < 16; ++it){
    int n = it*4 + r0;
    tile[n][c] = src[(size_t)n*64 + c];
  }
  __syncthreads();
  int j  = k0 + c;                          // global k (0..4095)
  int jl = j & 1023;
  int kap = (j & ~1023) + ((jl >> 8) << 8) + ((jl & 3) << 6) + ((jl >> 2) & 63);
  #pragma unroll
  for (int it = 0; it < 16; ++it){
    int d = it*4 + r0;
    float v = tile[c][d];
    u16 h = f2b(v);
    float lo = v - b2f(h);
    size_t o = ((size_t)b*64 + d)*4096 + kap;
    wThi[o] = h;
    wTlo[o] = f2b(lo);
  }
}

// ---- K1: fused mask-stream -> ballot bits (LDS) -> MFMA GEMM.
// Stream: 16 rows/wave, fully-coalesced 1KB float4 loads, 16 ballots/row ->
// 16 u64 words parked in wave-private LDS (row stride 17 u64 = bank spread).
// GEMM: per step one LDS byte/lane -> bf16 0/1 fragment (k permuted to match
// ballot order), B = wThi/wTlo (L2), deg via ones-MFMA. psum layout = R3.
__global__ __launch_bounds__(256) void k_mask(
    const float* __restrict__ ww, const float* __restrict__ wem,
    const float* __restrict__ d0, const float* __restrict__ d1,
    const float* __restrict__ wes, const float* __restrict__ wop,
    const u16* __restrict__ wThi, const u16* __restrict__ wTlo,
    const float* __restrict__ nh, const float* __restrict__ Wg, const float* __restrict__ bg,
    const float* __restrict__ Wf, const float* __restrict__ Wupd, const float* __restrict__ Wo,
    u16* __restrict__ psumB, int* __restrict__ pcntB,
    u16* __restrict__ psumD, int* __restrict__ pcntD,
    u64* __restrict__ bitOp, float* __restrict__ ghat,
    uint32_t* __restrict__ pkWf, uint32_t* __restrict__ pkWu, uint32_t* __restrict__ pkWo){
  __shared__ u64 sb[4][272];                      // 16 rows x 17 u64 per wave
  int tid = threadIdx.x, wave = tid >> 6, lane = tid & 63;
  int bid = blockIdx.x;
  if (bid >= 768){
    if (bid >= 1024){
      int aux = bid - 1024;                        // 0..16
      if (aux == 16){                              // ghat
        if (tid < 128){
          int b = tid >> 6, h = tid & 63;
          float g = bg[h];
          for (int d = 0; d < 64; ++d) g += nh[b*64 + d] * Wg[d*64 + h];
          float ss = g * g;
          #pragma unroll
          for (int o = 32; o > 0; o >>= 1) ss += __shfl_xor(ss, o, 64);
          ghat[b*64 + h] = g / (sqrtf(ss) + 1e-30f);
        }
        return;
      }
      for (int k = tid; k < 1024; k += 256){       // bf16-pair weight packing
        int i = aux*1024 + k;                      // 0..16383
        const float* src; uint32_t* dst; int li;
        if (i < 8192){ src = Wf; dst = pkWf; li = i; }
        else if (i < 14336){ src = Wupd; dst = pkWu; li = i - 8192; }
        else { src = Wo; dst = pkWo; li = i - 14336; }
        int k2 = li >> 6, ln = li & 63;
        dst[li] = (uint32_t)f2b(src[(2*k2)*64 + ln]) | ((uint32_t)f2b(src[(2*k2+1)*64 + ln]) << 16);
      }
      return;
    }
    // wop bits: wes & wop -> bitOp[n][o>>6]
    int w = (bid - 768)*4 + wave;                  // 0..1023
    int ng0 = w * 8;
    #pragma unroll
    for (int i = 0; i < 8; ++i){
      int n = ng0 + i;
      float vx = wop[(size_t)n*128 + lane];
      float vy = wop[(size_t)n*128 + 64 + lane];
      float e  = wes[n];
      u64 m0 = __ballot((e != 0.f) && (vx != 0.f));
      u64 m1 = __ballot((e != 0.f) && (vy != 0.f));
      if (lane == 0) bitOp[(size_t)n*2]     = m0;
      if (lane == 1) bitOp[(size_t)n*2 + 1] = m1;
    }
    return;
  }
  // ---- GEMM task setup (same mapping as R3)
  bool big; int wb, kOffW, tBase, tStride;
  const float *mArow, *mBrow; size_t ldm;
  u16* psArr; int* pcArr;
  if (bid < 512){
    int rowblk = bid >> 2, kq = bid & 3;
    int bb = rowblk >> 6;
    int grow = bb*4096 + (rowblk & 63)*64 + wave*16;   // global row 0..8191
    mArow = ww  + (size_t)grow*4096 + kq*1024;
    mBrow = wem + (size_t)grow*4096 + kq*1024;
    ldm = 4096; big = true;
    wb = bb; kOffW = kq*1024;
    tBase = grow*4 + kq; tStride = 4;
    psArr = psumB; pcArr = pcntB;
  } else {
    int i = bid - 512;
    int inst = i >> 6, r6 = i & 63;                    // inst: d0b0,d0b1,d1b0,d1b1
    int rowblkL = r6 >> 1, kh = r6 & 1;
    int prow = inst*2048 + rowblkL*64 + wave*16;       // psumD row space 0..8191
    const float* marr = (inst < 2) ? d0 : d1;
    int mrow = (inst < 2) ? prow : (prow - 4096);
    mArow = marr + (size_t)mrow*2048 + kh*1024;
    mBrow = mArow; ldm = 2048; big = false;
    wb = inst & 1; kOffW = ((inst >= 2) ? 2048 : 0) + kh*1024;
    tBase = prow*2 + kh; tStride = 2;
    psArr = psumD; pcArr = pcntD;
  }
  int col = lane & 15, oct = lane >> 4;
  u64* sbw = &sb[wave][0];
  // ---- Phase 1: stream 16 rows, ballot -> LDS words (1-row-deep pipeline)
  float4 a0, a1, a2, a3;
  float4 b0v = {0,0,0,0}, b1v = {0,0,0,0}, b2v = {0,0,0,0}, b3v = {0,0,0,0};
  {
    const float4* ra = (const float4*)mArow + lane;
    a0 = ra[0]; a1 = ra[64]; a2 = ra[128]; a3 = ra[192];
    if (big){
      const float4* rb = (const float4*)mBrow + lane;
      b0v = rb[0]; b1v = rb[64]; b2v = rb[128]; b3v = rb[192];
    }
  }
#define B4(i, va, vb) { \
  u64 m0 = __ballot((va.x != 0.f) && (!big || (vb.x != 0.f))); \
  u64 m1 = __ballot((va.y != 0.f) && (!big || (vb.y != 0.f))); \
  u64 m2 = __ballot((va.z != 0.f) && (!big || (vb.z != 0.f))); \
  u64 m3 = __ballot((va.w != 0.f) && (!big || (vb.w != 0.f))); \
  if (lane == (i)*4 + 0) myw = m0; \
  if (lane == (i)*4 + 1) myw = m1; \
  if (lane == (i)*4 + 2) myw = m2; \
  if (lane == (i)*4 + 3) myw = m3; }
  #pragma unroll 1
  for (int r = 0; r < 16; ++r){
    float4 ca0 = a0, ca1 = a1, ca2 = a2, ca3 = a3;
    float4 cb0 = b0v, cb1 = b1v, cb2 = b2v, cb3 = b3v;
    if (r < 15){
      const float4* ra = (const float4*)(mArow + (size_t)(r+1)*ldm) + lane;
      a0 = ra[0]; a1 = ra[64]; a2 = ra[128]; a3 = ra[192];
      if (big){
        const float4* rb = (const float4*)(mBrow + (size_t)(r+1)*ldm) + lane;
        b0v = rb[0]; b1v = rb[64]; b2v = rb[128]; b3v = rb[192];
      }
    }
    u64 myw = 0;
    B4(0, ca0, cb0) B4(1, ca1, cb1) B4(2, ca2, cb2) B4(3, ca3, cb3)
    if (lane < 16) sbw[r*17 + lane] = myw;
  }
#undef B4
  // ---- Phase 2: GEMM over 32 k-steps (k in ballot-permuted order).
  const u8* sbb = (const u8*)sbw;
  const u16* ph = wThi + ((size_t)wb*64 + col)*4096 + kOffW + oct*8;
  const u16* pl = wTlo + ((size_t)wb*64 + col)*4096 + kOffW + oct*8;
  f32x4 acc0 = {0.f,0.f,0.f,0.f}, acc1 = acc0, acc2 = acc0, acc3 = acc0, accD = acc0;
  union { uint32_t w[4]; bf16x8 v; } onesU;
  onesU.w[0] = onesU.w[1] = onesU.w[2] = onesU.w[3] = 0x3F803F80u;   // bf16 1.0 x8
  bf16x8 ones = onesU.v;
  // prefetch step 0
  bf16x8 h0 = *(const bf16x8*)ph;
  bf16x8 h1 = *(const bf16x8*)(ph + 65536);
  bf16x8 h2 = *(const bf16x8*)(ph + 131072);
  bf16x8 h3 = *(const bf16x8*)(ph + 196608);
  bf16x8 l0 = *(const bf16x8*)pl;
  bf16x8 l1 = *(const bf16x8*)(pl + 65536);
  bf16x8 l2 = *(const bf16x8*)(pl + 131072);
  bf16x8 l3 = *(const bf16x8*)(pl + 196608);
  uint32_t byn = sbb[col*136 + oct];               // s=0: w=oct>>3=0, bp=oct
  #pragma unroll 1
  for (int s = 0; s < 32; ++s){
    uint32_t by = byn;
    bf16x8 bh0 = h0, bh1 = h1, bh2 = h2, bh3 = h3;
    bf16x8 bl0 = l0, bl1 = l1, bl2 = l2, bl3 = l3;
    if (s < 31){
      int sn = s + 1;
      int t4 = ((sn & 7) << 2) + oct;
      byn = sbb[col*136 + (((sn >> 3) << 2) + (t4 >> 3))*8 + (t4 & 7)];
      const u16* qh = ph + (size_t)sn*32;
      h0 = *(const bf16x8*)qh;
      h1 = *(const bf16x8*)(qh + 65536);
      h2 = *(const bf16x8*)(qh + 131072);
      h3 = *(const bf16x8*)(qh + 196608);
      const u16* ql = pl + (size_t)sn*32;
      l0 = *(const bf16x8*)ql;
      l1 = *(const bf16x8*)(ql + 65536);
      l2 = *(const bf16x8*)(ql + 131072);
      l3 = *(const bf16x8*)(ql + 196608);
    }
    union { uint32_t w[4]; bf16x8 v; } af;
    af.w[0] = ((by &   1u) ? 0x3F80u : 0u) | ((by &   2u) ? 0x3F800000u : 0u);
    af.w[1] = ((by &   4u) ? 0x3F80u : 0u) | ((by &   8u) ? 0x3F800000u : 0u);
    af.w[2] = ((by &  16u) ? 0x3F80u : 0u) | ((by &  32u) ? 0x3F800000u : 0u);
    af.w[3] = ((by &  64u) ? 0x3F80u : 0u) | ((by & 128u) ? 0x3F800000u : 0u);
    bf16x8 a = af.v;
    acc0 = MFMA16(a, bh0, acc0);
    acc0 = MFMA16(a, bl0, acc0);
    acc1 = MFMA16(a, bh1, acc1);
    acc1 = MFMA16(a, bl1, acc1);
    acc2 = MFMA16(a, bh2, acc2);
    acc2 = MFMA16(a, bl2, acc2);
    acc3 = MFMA16(a, bh3, acc3);
    acc3 = MFMA16(a, bl3, acc3);
    accD = MFMA16(a, ones, accD);
  }
  // ---- write psum (bf16) + deg counts. D: row=oct*4+r, col=lane&15.
  #pragma unroll
  for (int r = 0; r < 4; ++r){
    size_t t = (size_t)tBase + (size_t)(oct*4 + r) * tStride;
    u16* prow = psArr + t*64;
    prow[ 0 + col] = f2b(acc0[r]);
    prow[16 + col] = f2b(acc1[r]);
    prow[32 + col] = f2b(acc2[r]);
    prow[48 + col] = f2b(acc3[r]);
    if (col == 0) pcArr[t] = (int)(accD[r] + 0.5f);
  }
}

// ---- K2: combine partials + linear transform + c*bias + l2n (unchanged)
__global__ __launch_bounds__(256) void k_fin(
    const u16* __restrict__ psumB, const int* __restrict__ pcntB,
    const u16* __restrict__ psumD, const int* __restrict__ pcntD,
    const float* __restrict__ Wwk, const float* __restrict__ bwk,
    const float* __restrict__ Wws, const float* __restrict__ bws,
    u16* __restrict__ wwkn, u16* __restrict__ wwsn){
  __shared__ float sWk[4096], sWs[4096];
  int tid = threadIdx.x, lane = tid & 63, wave = tid >> 6;
  for (int i = tid; i < 1024; i += 256){
    ((float4*)sWk)[i] = ((const float4*)Wwk)[i];
    ((float4*)sWs)[i] = ((const float4*)Wws)[i];
  }
  __syncthreads();
  for (int r = 0; r < 4; ++r){
    int wid = blockIdx.x*4 + wave + r*4096;        // 0..16383
    float S; float y; const float* sW; u16* outp; size_t oidx;
    if (wid < 8192){                               // big rows (word_w_k)
      S = b2f(psumB[((size_t)wid*4 + 0)*64 + lane]) + b2f(psumB[((size_t)wid*4 + 1)*64 + lane])
        + b2f(psumB[((size_t)wid*4 + 2)*64 + lane]) + b2f(psumB[((size_t)wid*4 + 3)*64 + lane]);
      int T = pcntB[wid*4] + pcntB[wid*4 + 1] + pcntB[wid*4 + 2] + pcntB[wid*4 + 3];
      y = (float)T * bwk[lane]; sW = sWk; outp = wwkn; oidx = wid;
    } else {                                       // dep rows (word_w_s)
      int rp = wid - 8192;
      S = b2f(psumD[((size_t)rp*2 + 0)*64 + lane]) + b2f(psumD[((size_t)rp*2 + 1)*64 + lane]);
      int T = pcntD[rp*2] + pcntD[rp*2 + 1];
      y = (float)T * bws[lane]; sW = sWs; outp = wwsn;
      int b, n;
      if (rp < 4096){ b = rp >> 11; n = rp & 2047; }
      else { int rr = rp - 4096; b = rr >> 11; n = 2048 + (rr & 2047); }
      oidx = (size_t)b*4096 + n;
    }
    #pragma unroll 8
    for (int d = 0; d < 64; ++d) y += __shfl(S, d, 64) * sW[d*64 + lane];
    float ss = y * y;
    #pragma unroll
    for (int o = 32; o > 0; o >>= 1) ss += __shfl_xor(ss, o, 64);
    outp[oidx*64 + lane] = f2b(y / (sqrtf(ss) + 1e-30f));
  }
}

// ---- K3: gate + update + Wo projection (unchanged)
__global__ __launch_bounds__(256, 2) void k_update(
    const float* __restrict__ w0, const float* __restrict__ w1,
    const float* __restrict__ gw, const float* __restrict__ ghat,
    const u16* __restrict__ wwkn, const u16* __restrict__ wwsn,
    const uint32_t* __restrict__ pkWf, const uint32_t* __restrict__ pkWu,
    const uint32_t* __restrict__ pkWo,
    const float* __restrict__ bf, const float* __restrict__ bupd, const float* __restrict__ bo,
    float* __restrict__ out, float* __restrict__ WUo){
  __shared__ uint32_t pWf[8192];    // 32 KB
  __shared__ uint32_t pWu[6144];    // 24 KB
  __shared__ uint32_t pWo[2048];    // 8 KB
  __shared__ float xsh[4][256];     // 4 KB
  int tid = threadIdx.x;
  for (int i = tid; i < 2048; i += 256) ((uint4*)pWf)[i] = ((const uint4*)pkWf)[i];
  for (int i = tid; i < 1536; i += 256) ((uint4*)pWu)[i] = ((const uint4*)pkWu)[i];
  for (int i = tid; i < 512;  i += 256) ((uint4*)pWo)[i] = ((const uint4*)pkWo)[i];
  __syncthreads();
  int lane = tid & 63, wave = tid >> 6;
  float bff = bf[lane], bup = bupd[lane], boo = bo[lane];
  float aw[4], wgv[4], wk[4], wsv[4];
  #pragma unroll
  for (int t = 0; t < 4; ++t){
    int row = blockIdx.x*4 + wave + t*2048;
    int b = row >> 12, n = row & 4095;
    aw[t] = (n < 2048) ? w0[((size_t)(b*2048 + n))*64 + lane]
                       : w1[((size_t)(b*2048 + n - 2048))*64 + lane];
    float gvv = gw[b*4096 + n];
    wgv[t] = (gvv != 0.f) ? ghat[b*64 + lane] : 0.f;
    wk[t]  = b2f(wwkn[(size_t)row*64 + lane]);
    wsv[t] = b2f(wwsn[(size_t)row*64 + lane]);
  }
  #pragma unroll
  for (int t = 0; t < 4; ++t){
    int row = blockIdx.x*4 + wave + t*2048;
    int b = row >> 12, n = row & 4095;
    xsh[wave][lane] = aw[t]; xsh[wave][64 + lane] = wgv[t];
    xsh[wave][128 + lane] = wk[t]; xsh[wave][192 + lane] = wsv[t];
    float f = bff, u = bup;
    #pragma unroll 8
    for (int k2 = 0; k2 < 32; ++k2){
      float2 xv = *(const float2*)&xsh[wave][2*k2];
      uint32_t wf = pWf[k2*64 + lane];
      f += xv.x * b2f((u16)wf) + xv.y * b2f((u16)(wf >> 16));
    }
    #pragma unroll 8
    for (int k2 = 32; k2 < 128; ++k2){
      float2 xv = *(const float2*)&xsh[wave][2*k2];
      uint32_t wf = pWf[k2*64 + lane];
      uint32_t wu = pWu[(k2 - 32)*64 + lane];
      f += xv.x * b2f((u16)wf) + xv.y * b2f((u16)(wf >> 16));
      u += xv.x * b2f((u16)wu) + xv.y * b2f((u16)(wu >> 16));
    }
    f = sigmoidf(f);
    u = fmaxf(u, 0.f);
    float wu = fmaxf(f, 0.2f) * aw[t] + (1.f - f) * u;
    out[((size_t)b*4224 + n)*64 + lane] = wu;
    float o = boo;
    #pragma unroll 8
    for (int k2 = 0; k2 < 32; ++k2){
      uint32_t wo2 = pWo[k2*64 + lane];
      o += __shfl(wu, 2*k2, 64) * b2f((u16)wo2) + __shfl(wu, 2*k2 + 1, 64) * b2f((u16)(wo2 >> 16));
    }
    WUo[(size_t)row*64 + lane] = o;
  }
}

// ---- K4: fused op aggregation + epilogue (unchanged). One block per (b,o).
__global__ __launch_bounds__(256) void k_opfin(
    const u64* __restrict__ bitOp, const float* __restrict__ WUo,
    const float* __restrict__ opE,
    const float* __restrict__ Wf2, const float* __restrict__ bf2,
    const float* __restrict__ Wout, const float* __restrict__ bout,
    float* __restrict__ out){
  __shared__ float sW2[8192];   // 32 KB
  __shared__ float sWo[4096];   // 16 KB
  __shared__ int q[4][96];
  __shared__ float sacc[4][64];
  __shared__ int scnt[4];
  __shared__ float xsh[128];
  int tid = threadIdx.x, lane = tid & 63, wave = tid >> 6;
  for (int i = tid; i < 2048; i += 256) ((float4*)sW2)[i] = ((const float4*)Wf2)[i];
  for (int i = tid; i < 1024; i += 256) ((float4*)sWo)[i] = ((const float4*)Wout)[i];
  int rowIdx = blockIdx.x;                      // b*128 + o
  int b = rowIdx >> 7, o = rowIdx & 127;
  int wrd = o >> 6, bit = o & 63;
  const u64* bp = bitOp + (size_t)b*8192 + (size_t)wave*2048 + wrd;
  u64 lt = (1ULL << lane) - 1ULL;
  u64 vv[16];
  #pragma unroll
  for (int it = 0; it < 16; ++it) vv[it] = bp[(size_t)(it*64 + lane)*2];
  int cnt = 0;
  #pragma unroll
  for (int it = 0; it < 16; ++it){
    bool nz = (vv[it] >> bit) & 1ULL;
    u64 m = __ballot(nz);
    if (nz) q[wave][cnt + (int)__popcll(m & lt)] = wave*1024 + it*64 + lane;
    cnt += (int)__popcll(m);
  }
  const float* Xb = WUo + (size_t)b*4096*64 + lane;
  float acc = 0.f;
  int i = 0;
  for (; i + 8 <= cnt; i += 8){
    int4 c0 = *(const int4*)&q[wave][i];
    int4 c1 = *(const int4*)&q[wave][i + 4];
    float v0 = Xb[(size_t)c0.x*64], v1 = Xb[(size_t)c0.y*64];
    float v2 = Xb[(size_t)c0.z*64], v3 = Xb[(size_t)c0.w*64];
    float v4 = Xb[(size_t)c1.x*64], v5 = Xb[(size_t)c1.y*64];
    float v6 = Xb[(size_t)c1.z*64], v7 = Xb[(size_t)c1.w*64];
    acc += ((v0 + v1) + (v2 + v3)) + ((v4 + v5) + (v6 + v7));
  }
  for (; i < cnt; ++i) acc += Xb[(size_t)q[wave][i]*64];
  sacc[wave][lane] = acc;
  if (lane == 0) scnt[wave] = cnt;
  __syncthreads();
  if (wave == 0){
    float t = sacc[0][lane] + sacc[1][lane] + sacc[2][lane] + sacc[3][lane];
    float deg = (float)(scnt[0] + scnt[1] + scnt[2] + scnt[3]);
    float wo = t / (deg + 1e-30f);
    float e  = opE[(size_t)rowIdx*64 + lane];
    xsh[lane] = e; xsh[64 + lane] = wo;
    float f = bf2[lane], u = bout[lane];
    #pragma unroll 8
    for (int k = 0; k < 128; ++k) f += xsh[k] * sW2[k*64 + lane];
    #pragma unroll 8
    for (int d = 0; d < 64; ++d)  u += xsh[64 + d] * sWo[d*64 + lane];
    f = sigmoidf(f);
    u = fmaxf(u, 0.f);
    float res = fmaxf(f, 0.2f) * e + (1.f - f) * u;
    out[((size_t)b*4224 + 4096 + o)*64 + lane] = res;
  }
}

extern "C" void kernel_launch(void* const* d_in, const int* in_sizes, int n_in,
                              void* d_out, int out_size, void* d_ws, size_t ws_size,
                              hipStream_t stream){
  const float* w0   = (const float*)d_in[0];
  const float* w1   = (const float*)d_in[1];
  const float* nh   = (const float*)d_in[2];
  const float* opE  = (const float*)d_in[3];
  const float* wes  = (const float*)d_in[4];
  const float* wem  = (const float*)d_in[5];
  const float* wop  = (const float*)d_in[6];
  const float* ww   = (const float*)d_in[7];
  const float* d0   = (const float*)d_in[8];
  const float* d1   = (const float*)d_in[9];
  const float* gw   = (const float*)d_in[10];
  const float* Wg   = (const float*)d_in[11];
  const float* bg   = (const float*)d_in[12];
  const float* Wwk  = (const float*)d_in[13];
  const float* bwk  = (const float*)d_in[14];
  const float* Wws  = (const float*)d_in[15];
  const float* bws  = (const float*)d_in[16];
  const float* Wo   = (const float*)d_in[17];
  const float* bo   = (const float*)d_in[18];
  const float* Wupd = (const float*)d_in[19];
  const float* bupd = (const float*)d_in[20];
  const float* Wf   = (const float*)d_in[21];
  const float* bf   = (const float*)d_in[22];
  const float* Wf2  = (const float*)d_in[23];
  const float* bf2  = (const float*)d_in[24];
  const float* Wout = (const float*)d_in[25];
  const float* bout = (const float*)d_in[26];

  float* ws    = (float*)d_ws;
  float* ghat  = ws;                             // 128
  uint32_t* pkWf = (uint32_t*)(ws + 128);        // 8192 u32
  uint32_t* pkWu = (uint32_t*)(ws + 8320);       // 6144 u32
  uint32_t* pkWo = (uint32_t*)(ws + 14464);      // 2048 u32
  u64*  bitOp  = (u64*)(ws + 16512);             // 16384 u64 (32768 f32)
  u16*  psumB  = (u16*)(ws + 49280);             // 32768 chunks x 64 u16 (1048576 f32)
  int*  pcntB  = (int*)(ws + 1097856);           // 32768 int
  u16*  psumD  = (u16*)(ws + 1130624);           // 16384 chunks x 64 u16 (524288 f32)
  int*  pcntD  = (int*)(ws + 1654912);           // 16384 int
  u16*  wwkn   = (u16*)(ws + 1671296);           // 524288 u16 (262144 f32)
  u16*  wwsn   = (u16*)(ws + 1933440);           // 524288 u16
  float* WUo   = ws + 2195584;                   // 524288 f32
  u16*  wThi   = (u16*)(ws + 2719872);           // 524288 u16 (262144 f32)
  u16*  wTlo   = (u16*)(ws + 2982016);           // 524288 u16 -> ws end 3244160 f32
  float* out   = (float*)d_out;

  k_prep<<<128, 256, 0, stream>>>(w0, w1, wThi, wTlo);
  k_mask<<<1041, 256, 0, stream>>>(ww, wem, d0, d1, wes, wop, wThi, wTlo,
                                   nh, Wg, bg, Wf, Wupd, Wo,
                                   psumB, pcntB, psumD, pcntD,
                                   bitOp, ghat, pkWf, pkWu, pkWo);
  k_fin<<<1024, 256, 0, stream>>>(psumB, pcntB, psumD, pcntD,
                                  Wwk, bwk, Wws, bws, wwkn, wwsn);
  k_update<<<512, 256, 0, stream>>>(w0, w1, gw, ghat, wwkn, wwsn,
                                    pkWf, pkWu, pkWo, bf, bupd, bo, out, WUo);
  k_opfin<<<256, 256, 0, stream>>>(bitOp, WUo, opE, Wf2, bf2, Wout, bout, out);
}

// Round 5
// 437.693 us; speedup vs baseline: 1.1784x; 1.1784x over previous
//
#include <hip/hip_runtime.h>
#include <cstdint>

typedef unsigned short u16;
typedef unsigned long long u64;

__device__ __forceinline__ u16 f2b(float f){
  union { float f; uint32_t i; } v; v.f = f;
  uint32_t r = v.i + 0x7FFFu + ((v.i >> 16) & 1u);   // RNE
  return (u16)(r >> 16);
}
__device__ __forceinline__ float b2f(u16 u){
  union { uint32_t i; float f; } v; v.i = ((uint32_t)u) << 16; return v.f;
}
__device__ __forceinline__ float sigmoidf(float x){ return 1.0f / (1.0f + __expf(-x)); }

// ---- K1: persistent fused mask-stream + register-gather.
// 2048 work blocks x 4 waves; each wave runs 6 chunk-tasks (t = wid + it*8192).
// Per task: ballot current masks -> LDS queue; issue NEXT task's masks (they
// stay in flight across the whole gather); gather w-rows to REGISTERS in
// 16-deep double-buffered batches (compiler emits counted vmcnt waits; no
// vmcnt(0) drain anywhere in the loop). Aux blocks: wop bits / packing / ghat.
__global__ __launch_bounds__(256) void k_bits(
    const float* __restrict__ ww, const float* __restrict__ wem,
    const float* __restrict__ d0, const float* __restrict__ d1,
    const float* __restrict__ wes, const float* __restrict__ wop,
    const float* __restrict__ w0, const float* __restrict__ w1,
    const float* __restrict__ nh, const float* __restrict__ Wg, const float* __restrict__ bg,
    const float* __restrict__ Wf, const float* __restrict__ Wupd, const float* __restrict__ Wo,
    u16* __restrict__ psumB, int* __restrict__ pcntB,
    u16* __restrict__ psumD, int* __restrict__ pcntD,
    u64* __restrict__ bitOp, float* __restrict__ ghat,
    uint32_t* __restrict__ pkWf, uint32_t* __restrict__ pkWu, uint32_t* __restrict__ pkWo){
  __shared__ int q[4][288];
  int tid = threadIdx.x, wave = tid >> 6, lane = tid & 63;
  int bid = blockIdx.x;
  if (bid >= 2048){
    if (bid >= 2304){
      int aux = bid - 2304;                        // 0..16
      if (aux == 16){                              // ghat
        if (tid < 128){
          int b = tid >> 6, h = tid & 63;
          float g = bg[h];
          for (int d = 0; d < 64; ++d) g += nh[b*64 + d] * Wg[d*64 + h];
          float ss = g * g;
          #pragma unroll
          for (int o = 32; o > 0; o >>= 1) ss += __shfl_xor(ss, o, 64);
          ghat[b*64 + h] = g / (sqrtf(ss) + 1e-30f);
        }
        return;
      }
      for (int k = tid; k < 1024; k += 256){       // bf16-pair weight packing
        int i = aux*1024 + k;                      // 0..16383
        const float* src; uint32_t* dst; int li;
        if (i < 8192){ src = Wf; dst = pkWf; li = i; }
        else if (i < 14336){ src = Wupd; dst = pkWu; li = i - 8192; }
        else { src = Wo; dst = pkWo; li = i - 14336; }
        int k2 = li >> 6, ln = li & 63;
        dst[li] = (uint32_t)f2b(src[(2*k2)*64 + ln]) | ((uint32_t)f2b(src[(2*k2+1)*64 + ln]) << 16);
      }
      return;
    }
    // wop bits: wes & wop -> bitOp[n][o>>6]
    int w = (bid - 2048)*4 + wave;                 // 0..1023
    int ng0 = w * 8;
    #pragma unroll
    for (int i = 0; i < 8; ++i){
      int n = ng0 + i;
      float vx = wop[(size_t)n*128 + lane];
      float vy = wop[(size_t)n*128 + 64 + lane];
      float e  = wes[n];
      u64 m0 = __ballot((e != 0.f) && (vx != 0.f));
      u64 m1 = __ballot((e != 0.f) && (vy != 0.f));
      if (lane == 0) bitOp[(size_t)n*2]     = m0;
      if (lane == 1) bitOp[(size_t)n*2 + 1] = m1;
    }
    return;
  }
  int wid = __builtin_amdgcn_readfirstlane(bid*4 + wave);   // wave-uniform -> SGPR
  float4 a0, a1, a2, a3, b0v, b1v, b2v, b3v;
#define ISSUE_MASKS(tt) { \
  int t_ = (tt); \
  if (t_ < 32768){ \
    int row_ = t_ >> 2, ch_ = t_ & 3; \
    const float4* ra_ = (const float4*)(ww  + (size_t)row_*4096 + ch_*1024) + lane; \
    const float4* rb_ = (const float4*)(wem + (size_t)row_*4096 + ch_*1024) + lane; \
    a0 = ra_[0]; a1 = ra_[64]; a2 = ra_[128]; a3 = ra_[192]; \
    b0v = rb_[0]; b1v = rb_[64]; b2v = rb_[128]; b3v = rb_[192]; \
  } else { \
    int idx_ = t_ - 32768, rowp_ = idx_ >> 1, ch_ = idx_ & 1; \
    const float* A_; \
    if (rowp_ < 4096) A_ = d0 + (size_t)rowp_*2048 + ch_*1024; \
    else { int rr_ = rowp_ - 4096; A_ = d1 + (size_t)rr_*2048 + ch_*1024; } \
    const float4* ra_ = (const float4*)A_ + lane; \
    a0 = ra_[0]; a1 = ra_[64]; a2 = ra_[128]; a3 = ra_[192]; \
  } }
  ISSUE_MASKS(wid)                                  // task 0 is always big (wid<8192)
  #pragma unroll 1
  for (int it = 0; it < 6; ++it){
    int t = wid + it*8192;
    bool big = (t < 32768);
    // ---- gather params (wave-uniform scalars)
    const float *sA, *sB;
    int jbase, thresh;
    u16* ps; int* pc;
    if (big){
      int row = t >> 2, chunk = t & 3;
      int b = row >> 12;
      sA = w0 + (size_t)b*131072;
      sB = w1 + (size_t)b*131072 - 131072;
      jbase = chunk*1024; thresh = 2048;
      ps = psumB + (size_t)t*64; pc = pcntB + t;
    } else {
      int idx = t - 32768, rowp = idx >> 1, chunk = idx & 1;
      if (rowp < 4096){ int b = rowp >> 11; sA = w0 + (size_t)b*131072; }
      else { int rr = rowp - 4096, b = rr >> 11; sA = w1 + (size_t)b*131072; }
      sB = sA;
      jbase = chunk*1024; thresh = 4096;            // never hits sB
      ps = psumD + (size_t)idx*64; pc = pcntD + idx;
    }
    // ---- ballot current masks -> 16 words (lanes 0..15 hold one each)
    u64 myw = 0;
#define B4(i, va, vb) { \
  u64 m0 = __ballot((va.x != 0.f) && (!big || (vb.x != 0.f))); \
  u64 m1 = __ballot((va.y != 0.f) && (!big || (vb.y != 0.f))); \
  u64 m2 = __ballot((va.z != 0.f) && (!big || (vb.z != 0.f))); \
  u64 m3 = __ballot((va.w != 0.f) && (!big || (vb.w != 0.f))); \
  if (lane == (i)*4 + 0) myw = m0; \
  if (lane == (i)*4 + 1) myw = m1; \
  if (lane == (i)*4 + 2) myw = m2; \
  if (lane == (i)*4 + 3) myw = m3; }
    B4(0, a0, b0v) B4(1, a1, b1v) B4(2, a2, b2v) B4(3, a3, b3v)
#undef B4
    // ---- compact nonzero chunk-cols into LDS queue
    int c = __popcll(myw);
    int pre = c;
    #pragma unroll
    for (int off = 1; off < 64; off <<= 1){
      int tt = __shfl_up(pre, off, 64);
      if (lane >= off) pre += tt;
    }
    int total = __shfl(pre, 63, 64);
    int base = pre - c;
    int colhi = (lane >> 2) * 256 + (lane & 3);
    u64 m = myw;
    while (m){
      int p = __builtin_ctzll(m); m &= m - 1;
      q[wave][base++] = colhi + p*4;
    }
    int totP = (total + 15) & ~15;
    if (lane < totP - total) q[wave][total + lane] = 0;   // pad (masked off later)
    // ---- issue NEXT task's masks NOW (in flight across the whole gather)
    if (it < 5) ISSUE_MASKS(t + 8192)
    // ---- register-gather, 16-deep double-buffered (no vmcnt(0) drains)
    float acc = 0.f;
    int nb = totP >> 4;
    float g0[16], g1[16];
#define GISS(arr, bi) { int bse = (bi) << 4; \
  _Pragma("unroll") for (int k2 = 0; k2 < 16; ++k2){ \
    int j = __builtin_amdgcn_readfirstlane(jbase + q[wave][bse + k2]); \
    const float* pp = ((j < thresh) ? sA : sB) + (size_t)j*64; \
    arr[k2] = pp[lane]; } }
#define GACC(arr, bi) { int bse = (bi) << 4; \
  _Pragma("unroll") for (int k2 = 0; k2 < 16; ++k2) \
    acc += (bse + k2 < total) ? arr[k2] : 0.f; }
    if (nb > 0) GISS(g0, 0)
    for (int bi = 0; bi < nb; bi += 2){
      if (bi + 1 < nb) GISS(g1, bi + 1)
      GACC(g0, bi)
      if (bi + 1 < nb){
        if (bi + 2 < nb) GISS(g0, bi + 2)
        GACC(g1, bi + 1)
      }
    }
#undef GISS
#undef GACC
    ps[lane] = f2b(acc);
    if (lane == 0) pc[0] = total;
  }
#undef ISSUE_MASKS
}

// ---- K2: FUSED fin+update. Per wave: 4 global rows. Phase A computes wk/ws
// in registers (Wwk/Wws staged in LDS); barrier; SAME LDS re-staged with the
// packed Wf/Wupd/Wo; phase B does gate+update+Wo projection. No wwkn/wwsn
// round-trip, one launch instead of two.
__global__ __launch_bounds__(256, 2) void k_mid(
    const u16* __restrict__ psumB, const int* __restrict__ pcntB,
    const u16* __restrict__ psumD, const int* __restrict__ pcntD,
    const float* __restrict__ Wwk, const float* __restrict__ bwk,
    const float* __restrict__ Wws, const float* __restrict__ bws,
    const float* __restrict__ w0, const float* __restrict__ w1,
    const float* __restrict__ gw, const float* __restrict__ ghat,
    const uint32_t* __restrict__ pkWf, const uint32_t* __restrict__ pkWu,
    const uint32_t* __restrict__ pkWo,
    const float* __restrict__ bf, const float* __restrict__ bupd, const float* __restrict__ bo,
    float* __restrict__ out, float* __restrict__ WUo){
  __shared__ uint32_t ldsU[16384];    // 64 KB union: {sWk,sWs} then {pWf,pWu,pWo}
  __shared__ float xsh[4][256];       // 4 KB
  int tid = threadIdx.x, lane = tid & 63, wave = tid >> 6;
  float* sWk = (float*)ldsU;          // [4096]
  float* sWs = (float*)ldsU + 4096;   // [4096]
  for (int i = tid; i < 1024; i += 256){
    ((float4*)sWk)[i] = ((const float4*)Wwk)[i];
    ((float4*)sWs)[i] = ((const float4*)Wws)[i];
  }
  __syncthreads();
  float bwkL = bwk[lane], bwsL = bws[lane];
  float wk[4], wsv[4], aw[4], wgv[4];
  #pragma unroll
  for (int t = 0; t < 4; ++t){
    int row = blockIdx.x*4 + wave + t*2048;        // global row 0..8191
    int b = row >> 12, n = row & 4095;
    // word_w_k: combine 4 big-chunk partials + deg*bias + W + l2n
    float S = b2f(psumB[((size_t)row*4 + 0)*64 + lane]) + b2f(psumB[((size_t)row*4 + 1)*64 + lane])
            + b2f(psumB[((size_t)row*4 + 2)*64 + lane]) + b2f(psumB[((size_t)row*4 + 3)*64 + lane]);
    int T = pcntB[row*4] + pcntB[row*4 + 1] + pcntB[row*4 + 2] + pcntB[row*4 + 3];
    float y = (float)T * bwkL;
    #pragma unroll 8
    for (int d = 0; d < 64; ++d) y += __shfl(S, d, 64) * sWk[d*64 + lane];
    float ss = y * y;
    #pragma unroll
    for (int o = 32; o > 0; o >>= 1) ss += __shfl_xor(ss, o, 64);
    wk[t] = y / (sqrtf(ss) + 1e-30f);
    // word_w_s: combine 2 dep-chunk partials
    int rp = (n < 2048) ? (b*2048 + n) : (4096 + b*2048 + (n - 2048));
    float S2 = b2f(psumD[((size_t)rp*2 + 0)*64 + lane]) + b2f(psumD[((size_t)rp*2 + 1)*64 + lane]);
    int T2 = pcntD[rp*2] + pcntD[rp*2 + 1];
    float y2 = (float)T2 * bwsL;
    #pragma unroll 8
    for (int d = 0; d < 64; ++d) y2 += __shfl(S2, d, 64) * sWs[d*64 + lane];
    float ss2 = y2 * y2;
    #pragma unroll
    for (int o = 32; o > 0; o >>= 1) ss2 += __shfl_xor(ss2, o, 64);
    wsv[t] = y2 / (sqrtf(ss2) + 1e-30f);
    // all_w row + goal term
    aw[t] = (n < 2048) ? w0[((size_t)(b*2048 + n))*64 + lane]
                       : w1[((size_t)(b*2048 + n - 2048))*64 + lane];
    wgv[t] = (gw[b*4096 + n] != 0.f) ? ghat[b*64 + lane] : 0.f;
  }
  __syncthreads();                     // all waves done reading sWk/sWs
  uint32_t* pWf = ldsU;                // [8192]  32 KB
  uint32_t* pWu = ldsU + 8192;         // [6144]  24 KB
  uint32_t* pWo = ldsU + 14336;        // [2048]   8 KB
  for (int i = tid; i < 2048; i += 256) ((uint4*)pWf)[i] = ((const uint4*)pkWf)[i];
  for (int i = tid; i < 1536; i += 256) ((uint4*)pWu)[i] = ((const uint4*)pkWu)[i];
  for (int i = tid; i < 512;  i += 256) ((uint4*)pWo)[i] = ((const uint4*)pkWo)[i];
  __syncthreads();
  float bff = bf[lane], bup = bupd[lane], boo = bo[lane];
  #pragma unroll
  for (int t = 0; t < 4; ++t){
    int row = blockIdx.x*4 + wave + t*2048;
    int b = row >> 12, n = row & 4095;
    xsh[wave][lane] = aw[t]; xsh[wave][64 + lane] = wgv[t];
    xsh[wave][128 + lane] = wk[t]; xsh[wave][192 + lane] = wsv[t];
    float f = bff, u = bup;
    #pragma unroll 8
    for (int k2 = 0; k2 < 32; ++k2){
      float2 xv = *(const float2*)&xsh[wave][2*k2];
      uint32_t wf = pWf[k2*64 + lane];
      f += xv.x * b2f((u16)wf) + xv.y * b2f((u16)(wf >> 16));
    }
    #pragma unroll 8
    for (int k2 = 32; k2 < 128; ++k2){
      float2 xv = *(const float2*)&xsh[wave][2*k2];
      uint32_t wf = pWf[k2*64 + lane];
      uint32_t wu = pWu[(k2 - 32)*64 + lane];
      f += xv.x * b2f((u16)wf) + xv.y * b2f((u16)(wf >> 16));
      u += xv.x * b2f((u16)wu) + xv.y * b2f((u16)(wu >> 16));
    }
    f = sigmoidf(f);
    u = fmaxf(u, 0.f);
    float wu = fmaxf(f, 0.2f) * aw[t] + (1.f - f) * u;
    out[((size_t)b*4224 + n)*64 + lane] = wu;
    float o = boo;
    #pragma unroll 8
    for (int k2 = 0; k2 < 32; ++k2){
      uint32_t wo2 = pWo[k2*64 + lane];
      o += __shfl(wu, 2*k2, 64) * b2f((u16)wo2) + __shfl(wu, 2*k2 + 1, 64) * b2f((u16)(wo2 >> 16));
    }
    WUo[(size_t)row*64 + lane] = o;
  }
}

// ---- K3: fused op aggregation + epilogue (unchanged, proven). One block per (b,o).
__global__ __launch_bounds__(256) void k_opfin(
    const u64* __restrict__ bitOp, const float* __restrict__ WUo,
    const float* __restrict__ opE,
    const float* __restrict__ Wf2, const float* __restrict__ bf2,
    const float* __restrict__ Wout, const float* __restrict__ bout,
    float* __restrict__ out){
  __shared__ float sW2[8192];   // 32 KB
  __shared__ float sWo[4096];   // 16 KB
  __shared__ int q[4][96];
  __shared__ float sacc[4][64];
  __shared__ int scnt[4];
  __shared__ float xsh[128];
  int tid = threadIdx.x, lane = tid & 63, wave = tid >> 6;
  for (int i = tid; i < 2048; i += 256) ((float4*)sW2)[i] = ((const float4*)Wf2)[i];
  for (int i = tid; i < 1024; i += 256) ((float4*)sWo)[i] = ((const float4*)Wout)[i];
  int rowIdx = blockIdx.x;                      // b*128 + o
  int b = rowIdx >> 7, o = rowIdx & 127;
  int wrd = o >> 6, bit = o & 63;
  const u64* bp = bitOp + (size_t)b*8192 + (size_t)wave*2048 + wrd;
  u64 lt = (1ULL << lane) - 1ULL;
  u64 vv[16];
  #pragma unroll
  for (int it = 0; it < 16; ++it) vv[it] = bp[(size_t)(it*64 + lane)*2];
  int cnt = 0;
  #pragma unroll
  for (int it = 0; it < 16; ++it){
    bool nz = (vv[it] >> bit) & 1ULL;
    u64 m = __ballot(nz);
    if (nz) q[wave][cnt + (int)__popcll(m & lt)] = wave*1024 + it*64 + lane;
    cnt += (int)__popcll(m);
  }
  const float* Xb = WUo + (size_t)b*4096*64 + lane;
  float acc = 0.f;
  int i = 0;
  for (; i + 8 <= cnt; i += 8){
    int4 c0 = *(const int4*)&q[wave][i];
    int4 c1 = *(const int4*)&q[wave][i + 4];
    float v0 = Xb[(size_t)c0.x*64], v1 = Xb[(size_t)c0.y*64];
    float v2 = Xb[(size_t)c0.z*64], v3 = Xb[(size_t)c0.w*64];
    float v4 = Xb[(size_t)c1.x*64], v5 = Xb[(size_t)c1.y*64];
    float v6 = Xb[(size_t)c1.z*64], v7 = Xb[(size_t)c1.w*64];
    acc += ((v0 + v1) + (v2 + v3)) + ((v4 + v5) + (v6 + v7));
  }
  for (; i < cnt; ++i) acc += Xb[(size_t)q[wave][i]*64];
  sacc[wave][lane] = acc;
  if (lane == 0) scnt[wave] = cnt;
  __syncthreads();
  if (wave == 0){
    float t = sacc[0][lane] + sacc[1][lane] + sacc[2][lane] + sacc[3][lane];
    float deg = (float)(scnt[0] + scnt[1] + scnt[2] + scnt[3]);
    float wo = t / (deg + 1e-30f);
    float e  = opE[(size_t)rowIdx*64 + lane];
    xsh[lane] = e; xsh[64 + lane] = wo;
    float f = bf2[lane], u = bout[lane];
    #pragma unroll 8
    for (int k = 0; k < 128; ++k) f += xsh[k] * sW2[k*64 + lane];
    #pragma unroll 8
    for (int d = 0; d < 64; ++d)  u += xsh[64 + d] * sWo[d*64 + lane];
    f = sigmoidf(f);
    u = fmaxf(u, 0.f);
    float res = fmaxf(f, 0.2f) * e + (1.f - f) * u;
    out[((size_t)b*4224 + 4096 + o)*64 + lane] = res;
  }
}

extern "C" void kernel_launch(void* const* d_in, const int* in_sizes, int n_in,
                              void* d_out, int out_size, void* d_ws, size_t ws_size,
                              hipStream_t stream){
  const float* w0   = (const float*)d_in[0];
  const float* w1   = (const float*)d_in[1];
  const float* nh   = (const float*)d_in[2];
  const float* opE  = (const float*)d_in[3];
  const float* wes  = (const float*)d_in[4];
  const float* wem  = (const float*)d_in[5];
  const float* wop  = (const float*)d_in[6];
  const float* ww   = (const float*)d_in[7];
  const float* d0   = (const float*)d_in[8];
  const float* d1   = (const float*)d_in[9];
  const float* gw   = (const float*)d_in[10];
  const float* Wg   = (const float*)d_in[11];
  const float* bg   = (const float*)d_in[12];
  const float* Wwk  = (const float*)d_in[13];
  const float* bwk  = (const float*)d_in[14];
  const float* Wws  = (const float*)d_in[15];
  const float* bws  = (const float*)d_in[16];
  const float* Wo   = (const float*)d_in[17];
  const float* bo   = (const float*)d_in[18];
  const float* Wupd = (const float*)d_in[19];
  const float* bupd = (const float*)d_in[20];
  const float* Wf   = (const float*)d_in[21];
  const float* bf   = (const float*)d_in[22];
  const float* Wf2  = (const float*)d_in[23];
  const float* bf2  = (const float*)d_in[24];
  const float* Wout = (const float*)d_in[25];
  const float* bout = (const float*)d_in[26];

  float* ws    = (float*)d_ws;
  float* ghat  = ws;                             // 128
  uint32_t* pkWf = (uint32_t*)(ws + 128);        // 8192 u32
  uint32_t* pkWu = (uint32_t*)(ws + 8320);       // 6144 u32
  uint32_t* pkWo = (uint32_t*)(ws + 14464);      // 2048 u32
  u64*  bitOp  = (u64*)(ws + 16512);             // 16384 u64 (32768 f32)
  u16*  psumB  = (u16*)(ws + 49280);             // 32768 chunks x 64 u16 (1048576 f32)
  int*  pcntB  = (int*)(ws + 1097856);           // 32768 int
  u16*  psumD  = (u16*)(ws + 1130624);           // 16384 chunks x 64 u16 (524288 f32)
  int*  pcntD  = (int*)(ws + 1654912);           // 16384 int
  float* WUo   = ws + 2195584;                   // 524288 f32 -> ws end 2719872 f32
  float* out   = (float*)d_out;

  k_bits<<<2321, 256, 0, stream>>>(ww, wem, d0, d1, wes, wop, w0, w1,
                                   nh, Wg, bg, Wf, Wupd, Wo,
                                   psumB, pcntB, psumD, pcntD,
                                   bitOp, ghat, pkWf, pkWu, pkWo);
  k_mid<<<512, 256, 0, stream>>>(psumB, pcntB, psumD, pcntD,
                                 Wwk, bwk, Wws, bws, w0, w1, gw, ghat,
                                 pkWf, pkWu, pkWo, bf, bupd, bo, out, WUo);
  k_opfin<<<256, 256, 0, stream>>>(bitOp, WUo, opE, Wf2, bf2, Wout, bout, out);
}

// Round 6
// 431.137 us; speedup vs baseline: 1.1963x; 1.0152x over previous
//
#include <hip/hip_runtime.h>
#include <cstdint>

typedef unsigned short u16;
typedef unsigned long long u64;

__device__ __forceinline__ u16 f2b(float f){
  union { float f; uint32_t i; } v; v.f = f;
  uint32_t r = v.i + 0x7FFFu + ((v.i >> 16) & 1u);   // RNE
  return (u16)(r >> 16);
}
__device__ __forceinline__ float b2f(u16 u){
  union { uint32_t i; float f; } v; v.i = ((uint32_t)u) << 16; return v.f;
}
__device__ __forceinline__ float sigmoidf(float x){ return 1.0f / (1.0f + __expf(-x)); }

// ---- K0: pack allw = concat(w0,w1) rows as bf16 pairs.
// wpk[b][j][p] (u32) = bf16(w[j][2p]) | bf16(w[j][2p+1])<<16; row = 128 B.
// 128 blocks x 256 threads; 64 rows/block, 4 threads/row (16 d each).
__global__ __launch_bounds__(256) void k_prep(
    const float* __restrict__ w0, const float* __restrict__ w1,
    uint32_t* __restrict__ wpk){
  int tid = threadIdx.x, blk = blockIdx.x;         // 0..127
  int b = blk >> 6;
  int j = (blk & 63) * 64 + (tid >> 2);
  int part = tid & 3;
  const float* src = (j < 2048) ? (w0 + ((size_t)(b*2048 + j))*64 + part*16)
                                : (w1 + ((size_t)(b*2048 + j - 2048))*64 + part*16);
  uint32_t* dst = wpk + ((size_t)b*4096 + j)*32 + part*8;
  float4 v0 = ((const float4*)src)[0];
  float4 v1 = ((const float4*)src)[1];
  float4 v2 = ((const float4*)src)[2];
  float4 v3 = ((const float4*)src)[3];
  uint4 o0, o1;
  o0.x = (uint32_t)f2b(v0.x) | ((uint32_t)f2b(v0.y) << 16);
  o0.y = (uint32_t)f2b(v0.z) | ((uint32_t)f2b(v0.w) << 16);
  o0.z = (uint32_t)f2b(v1.x) | ((uint32_t)f2b(v1.y) << 16);
  o0.w = (uint32_t)f2b(v1.z) | ((uint32_t)f2b(v1.w) << 16);
  o1.x = (uint32_t)f2b(v2.x) | ((uint32_t)f2b(v2.y) << 16);
  o1.y = (uint32_t)f2b(v2.z) | ((uint32_t)f2b(v2.w) << 16);
  o1.z = (uint32_t)f2b(v3.x) | ((uint32_t)f2b(v3.y) << 16);
  o1.w = (uint32_t)f2b(v3.z) | ((uint32_t)f2b(v3.w) << 16);
  ((uint4*)dst)[0] = o0;
  ((uint4*)dst)[1] = o1;
}

// ---- K1: persistent fused mask-stream + bf16 PAIR-gather.
// 2048 work blocks x 4 waves; 6 chunk-tasks/wave. Per task: ballot current
// masks -> LDS queue; issue NEXT task's masks; gather TWO 128B bf16 rows per
// instruction (lanes 0-31 row j_lo, lanes 32-63 row j_hi), 16-deep dbuf, no
// vmcnt(0) drains. Halves gather bytes+instructions vs f32 single-row.
__global__ __launch_bounds__(256) void k_bits(
    const float* __restrict__ ww, const float* __restrict__ wem,
    const float* __restrict__ d0, const float* __restrict__ d1,
    const float* __restrict__ wes, const float* __restrict__ wop,
    const uint32_t* __restrict__ wpk,
    const float* __restrict__ nh, const float* __restrict__ Wg, const float* __restrict__ bg,
    const float* __restrict__ Wf, const float* __restrict__ Wupd, const float* __restrict__ Wo,
    u16* __restrict__ psumB, int* __restrict__ pcntB,
    u16* __restrict__ psumD, int* __restrict__ pcntD,
    u64* __restrict__ bitOp, float* __restrict__ ghat,
    uint32_t* __restrict__ pkWf, uint32_t* __restrict__ pkWu, uint32_t* __restrict__ pkWo){
  __shared__ int q[4][288];
  int tid = threadIdx.x, wave = tid >> 6, lane = tid & 63;
  int bid = blockIdx.x;
  if (bid >= 2048){
    if (bid >= 2304){
      int aux = bid - 2304;                        // 0..16
      if (aux == 16){                              // ghat
        if (tid < 128){
          int b = tid >> 6, h = tid & 63;
          float g = bg[h];
          for (int d = 0; d < 64; ++d) g += nh[b*64 + d] * Wg[d*64 + h];
          float ss = g * g;
          #pragma unroll
          for (int o = 32; o > 0; o >>= 1) ss += __shfl_xor(ss, o, 64);
          ghat[b*64 + h] = g / (sqrtf(ss) + 1e-30f);
        }
        return;
      }
      for (int k = tid; k < 1024; k += 256){       // bf16-pair weight packing
        int i = aux*1024 + k;                      // 0..16383
        const float* src; uint32_t* dst; int li;
        if (i < 8192){ src = Wf; dst = pkWf; li = i; }
        else if (i < 14336){ src = Wupd; dst = pkWu; li = i - 8192; }
        else { src = Wo; dst = pkWo; li = i - 14336; }
        int k2 = li >> 6, ln = li & 63;
        dst[li] = (uint32_t)f2b(src[(2*k2)*64 + ln]) | ((uint32_t)f2b(src[(2*k2+1)*64 + ln]) << 16);
      }
      return;
    }
    // wop bits: wes & wop -> bitOp[n][o>>6]
    int w = (bid - 2048)*4 + wave;                 // 0..1023
    int ng0 = w * 8;
    #pragma unroll
    for (int i = 0; i < 8; ++i){
      int n = ng0 + i;
      float vx = wop[(size_t)n*128 + lane];
      float vy = wop[(size_t)n*128 + 64 + lane];
      float e  = wes[n];
      u64 m0 = __ballot((e != 0.f) && (vx != 0.f));
      u64 m1 = __ballot((e != 0.f) && (vy != 0.f));
      if (lane == 0) bitOp[(size_t)n*2]     = m0;
      if (lane == 1) bitOp[(size_t)n*2 + 1] = m1;
    }
    return;
  }
  int wid = bid*4 + wave;
  float4 a0, a1, a2, a3, b0v, b1v, b2v, b3v;
#define ISSUE_MASKS(tt) { \
  int t_ = (tt); \
  if (t_ < 32768){ \
    int row_ = t_ >> 2, ch_ = t_ & 3; \
    const float4* ra_ = (const float4*)(ww  + (size_t)row_*4096 + ch_*1024) + lane; \
    const float4* rb_ = (const float4*)(wem + (size_t)row_*4096 + ch_*1024) + lane; \
    a0 = ra_[0]; a1 = ra_[64]; a2 = ra_[128]; a3 = ra_[192]; \
    b0v = rb_[0]; b1v = rb_[64]; b2v = rb_[128]; b3v = rb_[192]; \
  } else { \
    int idx_ = t_ - 32768, rowp_ = idx_ >> 1, ch_ = idx_ & 1; \
    const float* A_; \
    if (rowp_ < 4096) A_ = d0 + (size_t)rowp_*2048 + ch_*1024; \
    else { int rr_ = rowp_ - 4096; A_ = d1 + (size_t)rr_*2048 + ch_*1024; } \
    const float4* ra_ = (const float4*)A_ + lane; \
    a0 = ra_[0]; a1 = ra_[64]; a2 = ra_[128]; a3 = ra_[192]; \
  } }
  ISSUE_MASKS(wid)                                  // task 0 is always big (wid<8192)
  int half = lane >> 5, dcol = lane & 31;
  #pragma unroll 1
  for (int it = 0; it < 6; ++it){
    int t = wid + it*8192;
    bool big = (t < 32768);
    // ---- gather params (wave-uniform)
    const uint32_t* wub;                           // allw pk base + jadd*32 + dcol
    u16* ps; int* pc;
    if (big){
      int row = t >> 2, chunk = t & 3;
      int b = row >> 12;
      wub = wpk + (size_t)b*131072 + (size_t)(chunk*1024)*32 + dcol;
      ps = psumB + (size_t)t*64; pc = pcntB + t;
    } else {
      int idx = t - 32768, rowp = idx >> 1, chunk = idx & 1;
      int b, jadd = chunk*1024;
      if (rowp < 4096){ b = rowp >> 11; }
      else { int rr = rowp - 4096; b = rr >> 11; jadd += 2048; }   // d1 -> w1 half of allw
      wub = wpk + (size_t)b*131072 + (size_t)jadd*32 + dcol;
      ps = psumD + (size_t)idx*64; pc = pcntD + idx;
    }
    // ---- ballot current masks -> 16 words (lanes 0..15 hold one each)
    u64 myw = 0;
#define B4(i, va, vb) { \
  u64 m0 = __ballot((va.x != 0.f) && (!big || (vb.x != 0.f))); \
  u64 m1 = __ballot((va.y != 0.f) && (!big || (vb.y != 0.f))); \
  u64 m2 = __ballot((va.z != 0.f) && (!big || (vb.z != 0.f))); \
  u64 m3 = __ballot((va.w != 0.f) && (!big || (vb.w != 0.f))); \
  if (lane == (i)*4 + 0) myw = m0; \
  if (lane == (i)*4 + 1) myw = m1; \
  if (lane == (i)*4 + 2) myw = m2; \
  if (lane == (i)*4 + 3) myw = m3; }
    B4(0, a0, b0v) B4(1, a1, b1v) B4(2, a2, b2v) B4(3, a3, b3v)
#undef B4
    // ---- compact nonzero chunk-cols into LDS queue
    int c = __popcll(myw);
    int pre = c;
    #pragma unroll
    for (int off = 1; off < 64; off <<= 1){
      int tt = __shfl_up(pre, off, 64);
      if (lane >= off) pre += tt;
    }
    int total = __shfl(pre, 63, 64);
    int base = pre - c;
    int colhi = (lane >> 2) * 256 + (lane & 3);
    u64 m = myw;
    while (m){
      int p = __builtin_ctzll(m); m &= m - 1;
      q[wave][base++] = colhi + p*4;
    }
    int totP = (total + 31) & ~31;                 // pad to 32 (2 rows x 16 loads)
    if (lane < totP - total) q[wave][total + lane] = 0;
    // ---- issue NEXT task's masks NOW (in flight across the whole gather)
    if (it < 5) ISSUE_MASKS(t + 8192)
    // ---- bf16 pair-gather: 16-deep dbuf, 32 rows/batch, no vmcnt(0) drains
    float accE = 0.f, accO = 0.f;
    int nb = totP >> 5;
    uint32_t g0[16], g1[16];
#define GISS(arr, bi) { int bse = (bi) << 5; \
  _Pragma("unroll") for (int k2 = 0; k2 < 16; ++k2){ \
    int j = q[wave][bse + 2*k2 + half]; \
    arr[k2] = wub[(size_t)j*32]; } }
#define GACC(arr, bi) { int bse = (bi) << 5; \
  _Pragma("unroll") for (int k2 = 0; k2 < 16; ++k2){ \
    bool v = (bse + 2*k2 + half) < total; \
    uint32_t wv = arr[k2]; \
    accE += v ? b2f((u16)wv) : 0.f; \
    accO += v ? b2f((u16)(wv >> 16)) : 0.f; } }
    if (nb > 0) GISS(g0, 0)
    for (int bi = 0; bi < nb; bi += 2){
      if (bi + 1 < nb) GISS(g1, bi + 1)
      GACC(g0, bi)
      if (bi + 1 < nb){
        if (bi + 2 < nb) GISS(g0, bi + 2)
        GACC(g1, bi + 1)
      }
    }
#undef GISS
#undef GACC
    // merge halves: lanes<32 get full (even,odd) d-pair sums
    accE += __shfl_xor(accE, 32, 64);
    accO += __shfl_xor(accO, 32, 64);
    if (lane < 32)
      ((uint32_t*)ps)[lane] = (uint32_t)f2b(accE) | ((uint32_t)f2b(accO) << 16);
    if (lane == 0) pc[0] = total;
  }
#undef ISSUE_MASKS
}

// ---- K2: FUSED fin+update (unchanged from R5).
__global__ __launch_bounds__(256, 2) void k_mid(
    const u16* __restrict__ psumB, const int* __restrict__ pcntB,
    const u16* __restrict__ psumD, const int* __restrict__ pcntD,
    const float* __restrict__ Wwk, const float* __restrict__ bwk,
    const float* __restrict__ Wws, const float* __restrict__ bws,
    const float* __restrict__ w0, const float* __restrict__ w1,
    const float* __restrict__ gw, const float* __restrict__ ghat,
    const uint32_t* __restrict__ pkWf, const uint32_t* __restrict__ pkWu,
    const uint32_t* __restrict__ pkWo,
    const float* __restrict__ bf, const float* __restrict__ bupd, const float* __restrict__ bo,
    float* __restrict__ out, float* __restrict__ WUo){
  __shared__ uint32_t ldsU[16384];    // 64 KB union: {sWk,sWs} then {pWf,pWu,pWo}
  __shared__ float xsh[4][256];       // 4 KB
  int tid = threadIdx.x, lane = tid & 63, wave = tid >> 6;
  float* sWk = (float*)ldsU;          // [4096]
  float* sWs = (float*)ldsU + 4096;   // [4096]
  for (int i = tid; i < 1024; i += 256){
    ((float4*)sWk)[i] = ((const float4*)Wwk)[i];
    ((float4*)sWs)[i] = ((const float4*)Wws)[i];
  }
  __syncthreads();
  float bwkL = bwk[lane], bwsL = bws[lane];
  float wk[4], wsv[4], aw[4], wgv[4];
  #pragma unroll
  for (int t = 0; t < 4; ++t){
    int row = blockIdx.x*4 + wave + t*2048;        // global row 0..8191
    int b = row >> 12, n = row & 4095;
    float S = b2f(psumB[((size_t)row*4 + 0)*64 + lane]) + b2f(psumB[((size_t)row*4 + 1)*64 + lane])
            + b2f(psumB[((size_t)row*4 + 2)*64 + lane]) + b2f(psumB[((size_t)row*4 + 3)*64 + lane]);
    int T = pcntB[row*4] + pcntB[row*4 + 1] + pcntB[row*4 + 2] + pcntB[row*4 + 3];
    float y = (float)T * bwkL;
    #pragma unroll 8
    for (int d = 0; d < 64; ++d) y += __shfl(S, d, 64) * sWk[d*64 + lane];
    float ss = y * y;
    #pragma unroll
    for (int o = 32; o > 0; o >>= 1) ss += __shfl_xor(ss, o, 64);
    wk[t] = y / (sqrtf(ss) + 1e-30f);
    int rp = (n < 2048) ? (b*2048 + n) : (4096 + b*2048 + (n - 2048));
    float S2 = b2f(psumD[((size_t)rp*2 + 0)*64 + lane]) + b2f(psumD[((size_t)rp*2 + 1)*64 + lane]);
    int T2 = pcntD[rp*2] + pcntD[rp*2 + 1];
    float y2 = (float)T2 * bwsL;
    #pragma unroll 8
    for (int d = 0; d < 64; ++d) y2 += __shfl(S2, d, 64) * sWs[d*64 + lane];
    float ss2 = y2 * y2;
    #pragma unroll
    for (int o = 32; o > 0; o >>= 1) ss2 += __shfl_xor(ss2, o, 64);
    wsv[t] = y2 / (sqrtf(ss2) + 1e-30f);
    aw[t] = (n < 2048) ? w0[((size_t)(b*2048 + n))*64 + lane]
                       : w1[((size_t)(b*2048 + n - 2048))*64 + lane];
    wgv[t] = (gw[b*4096 + n] != 0.f) ? ghat[b*64 + lane] : 0.f;
  }
  __syncthreads();                     // all waves done reading sWk/sWs
  uint32_t* pWf = ldsU;                // [8192]  32 KB
  uint32_t* pWu = ldsU + 8192;         // [6144]  24 KB
  uint32_t* pWo = ldsU + 14336;        // [2048]   8 KB
  for (int i = tid; i < 2048; i += 256) ((uint4*)pWf)[i] = ((const uint4*)pkWf)[i];
  for (int i = tid; i < 1536; i += 256) ((uint4*)pWu)[i] = ((const uint4*)pkWu)[i];
  for (int i = tid; i < 512;  i += 256) ((uint4*)pWo)[i] = ((const uint4*)pkWo)[i];
  __syncthreads();
  float bff = bf[lane], bup = bupd[lane], boo = bo[lane];
  #pragma unroll
  for (int t = 0; t < 4; ++t){
    int row = blockIdx.x*4 + wave + t*2048;
    int b = row >> 12, n = row & 4095;
    xsh[wave][lane] = aw[t]; xsh[wave][64 + lane] = wgv[t];
    xsh[wave][128 + lane] = wk[t]; xsh[wave][192 + lane] = wsv[t];
    float f = bff, u = bup;
    #pragma unroll 8
    for (int k2 = 0; k2 < 32; ++k2){
      float2 xv = *(const float2*)&xsh[wave][2*k2];
      uint32_t wf = pWf[k2*64 + lane];
      f += xv.x * b2f((u16)wf) + xv.y * b2f((u16)(wf >> 16));
    }
    #pragma unroll 8
    for (int k2 = 32; k2 < 128; ++k2){
      float2 xv = *(const float2*)&xsh[wave][2*k2];
      uint32_t wf = pWf[k2*64 + lane];
      uint32_t wu = pWu[(k2 - 32)*64 + lane];
      f += xv.x * b2f((u16)wf) + xv.y * b2f((u16)(wf >> 16));
      u += xv.x * b2f((u16)wu) + xv.y * b2f((u16)(wu >> 16));
    }
    f = sigmoidf(f);
    u = fmaxf(u, 0.f);
    float wu = fmaxf(f, 0.2f) * aw[t] + (1.f - f) * u;
    out[((size_t)b*4224 + n)*64 + lane] = wu;
    float o = boo;
    #pragma unroll 8
    for (int k2 = 0; k2 < 32; ++k2){
      uint32_t wo2 = pWo[k2*64 + lane];
      o += __shfl(wu, 2*k2, 64) * b2f((u16)wo2) + __shfl(wu, 2*k2 + 1, 64) * b2f((u16)(wo2 >> 16));
    }
    WUo[(size_t)row*64 + lane] = o;
  }
}

// ---- K3: fused op aggregation + epilogue (unchanged). One block per (b,o).
__global__ __launch_bounds__(256) void k_opfin(
    const u64* __restrict__ bitOp, const float* __restrict__ WUo,
    const float* __restrict__ opE,
    const float* __restrict__ Wf2, const float* __restrict__ bf2,
    const float* __restrict__ Wout, const float* __restrict__ bout,
    float* __restrict__ out){
  __shared__ float sW2[8192];   // 32 KB
  __shared__ float sWo[4096];   // 16 KB
  __shared__ int q[4][96];
  __shared__ float sacc[4][64];
  __shared__ int scnt[4];
  __shared__ float xsh[128];
  int tid = threadIdx.x, lane = tid & 63, wave = tid >> 6;
  for (int i = tid; i < 2048; i += 256) ((float4*)sW2)[i] = ((const float4*)Wf2)[i];
  for (int i = tid; i < 1024; i += 256) ((float4*)sWo)[i] = ((const float4*)Wout)[i];
  int rowIdx = blockIdx.x;                      // b*128 + o
  int b = rowIdx >> 7, o = rowIdx & 127;
  int wrd = o >> 6, bit = o & 63;
  const u64* bp = bitOp + (size_t)b*8192 + (size_t)wave*2048 + wrd;
  u64 lt = (1ULL << lane) - 1ULL;
  u64 vv[16];
  #pragma unroll
  for (int it = 0; it < 16; ++it) vv[it] = bp[(size_t)(it*64 + lane)*2];
  int cnt = 0;
  #pragma unroll
  for (int it = 0; it < 16; ++it){
    bool nz = (vv[it] >> bit) & 1ULL;
    u64 m = __ballot(nz);
    if (nz) q[wave][cnt + (int)__popcll(m & lt)] = wave*1024 + it*64 + lane;
    cnt += (int)__popcll(m);
  }
  const float* Xb = WUo + (size_t)b*4096*64 + lane;
  float acc = 0.f;
  int i = 0;
  for (; i + 8 <= cnt; i += 8){
    int4 c0 = *(const int4*)&q[wave][i];
    int4 c1 = *(const int4*)&q[wave][i + 4];
    float v0 = Xb[(size_t)c0.x*64], v1 = Xb[(size_t)c0.y*64];
    float v2 = Xb[(size_t)c0.z*64], v3 = Xb[(size_t)c0.w*64];
    float v4 = Xb[(size_t)c1.x*64], v5 = Xb[(size_t)c1.y*64];
    float v6 = Xb[(size_t)c1.z*64], v7 = Xb[(size_t)c1.w*64];
    acc += ((v0 + v1) + (v2 + v3)) + ((v4 + v5) + (v6 + v7));
  }
  for (; i < cnt; ++i) acc += Xb[(size_t)q[wave][i]*64];
  sacc[wave][lane] = acc;
  if (lane == 0) scnt[wave] = cnt;
  __syncthreads();
  if (wave == 0){
    float t = sacc[0][lane] + sacc[1][lane] + sacc[2][lane] + sacc[3][lane];
    float deg = (float)(scnt[0] + scnt[1] + scnt[2] + scnt[3]);
    float wo = t / (deg + 1e-30f);
    float e  = opE[(size_t)rowIdx*64 + lane];
    xsh[lane] = e; xsh[64 + lane] = wo;
    float f = bf2[lane], u = bout[lane];
    #pragma unroll 8
    for (int k = 0; k < 128; ++k) f += xsh[k] * sW2[k*64 + lane];
    #pragma unroll 8
    for (int d = 0; d < 64; ++d)  u += xsh[64 + d] * sWo[d*64 + lane];
    f = sigmoidf(f);
    u = fmaxf(u, 0.f);
    float res = fmaxf(f, 0.2f) * e + (1.f - f) * u;
    out[((size_t)b*4224 + 4096 + o)*64 + lane] = res;
  }
}

extern "C" void kernel_launch(void* const* d_in, const int* in_sizes, int n_in,
                              void* d_out, int out_size, void* d_ws, size_t ws_size,
                              hipStream_t stream){
  const float* w0   = (const float*)d_in[0];
  const float* w1   = (const float*)d_in[1];
  const float* nh   = (const float*)d_in[2];
  const float* opE  = (const float*)d_in[3];
  const float* wes  = (const float*)d_in[4];
  const float* wem  = (const float*)d_in[5];
  const float* wop  = (const float*)d_in[6];
  const float* ww   = (const float*)d_in[7];
  const float* d0   = (const float*)d_in[8];
  const float* d1   = (const float*)d_in[9];
  const float* gw   = (const float*)d_in[10];
  const float* Wg   = (const float*)d_in[11];
  const float* bg   = (const float*)d_in[12];
  const float* Wwk  = (const float*)d_in[13];
  const float* bwk  = (const float*)d_in[14];
  const float* Wws  = (const float*)d_in[15];
  const float* bws  = (const float*)d_in[16];
  const float* Wo   = (const float*)d_in[17];
  const float* bo   = (const float*)d_in[18];
  const float* Wupd = (const float*)d_in[19];
  const float* bupd = (const float*)d_in[20];
  const float* Wf   = (const float*)d_in[21];
  const float* bf   = (const float*)d_in[22];
  const float* Wf2  = (const float*)d_in[23];
  const float* bf2  = (const float*)d_in[24];
  const float* Wout = (const float*)d_in[25];
  const float* bout = (const float*)d_in[26];

  float* ws    = (float*)d_ws;
  float* ghat  = ws;                             // 128
  uint32_t* pkWf = (uint32_t*)(ws + 128);        // 8192 u32
  uint32_t* pkWu = (uint32_t*)(ws + 8320);       // 6144 u32
  uint32_t* pkWo = (uint32_t*)(ws + 14464);      // 2048 u32
  u64*  bitOp  = (u64*)(ws + 16512);             // 16384 u64 (32768 f32)
  u16*  psumB  = (u16*)(ws + 49280);             // 32768 chunks x 64 u16 (1048576 f32)
  int*  pcntB  = (int*)(ws + 1097856);           // 32768 int
  u16*  psumD  = (u16*)(ws + 1130624);           // 16384 chunks x 64 u16 (524288 f32)
  int*  pcntD  = (int*)(ws + 1654912);           // 16384 int
  float* WUo   = ws + 2195584;                   // 524288 f32
  uint32_t* wpk = (uint32_t*)(ws + 2719872);     // 262144 u32 -> ws end 2982016 f32
  float* out   = (float*)d_out;

  k_prep<<<128, 256, 0, stream>>>(w0, w1, wpk);
  k_bits<<<2321, 256, 0, stream>>>(ww, wem, d0, d1, wes, wop, wpk,
                                   nh, Wg, bg, Wf, Wupd, Wo,
                                   psumB, pcntB, psumD, pcntD,
                                   bitOp, ghat, pkWf, pkWu, pkWo);
  k_mid<<<512, 256, 0, stream>>>(psumB, pcntB, psumD, pcntD,
                                 Wwk, bwk, Wws, bws, w0, w1, gw, ghat,
                                 pkWf, pkWu, pkWo, bf, bupd, bo, out, WUo);
  k_opfin<<<256, 256, 0, stream>>>(bitOp, WUo, opE, Wf2, bf2, Wout, bout, out);
}

// Round 7
// 411.435 us; speedup vs baseline: 1.2536x; 1.0479x over previous
//
#include <hip/hip_runtime.h>
#include <cstdint>

typedef unsigned short u16;
typedef unsigned long long u64;

__device__ __forceinline__ u16 f2b(float f){
  union { float f; uint32_t i; } v; v.f = f;
  uint32_t r = v.i + 0x7FFFu + ((v.i >> 16) & 1u);   // RNE
  return (u16)(r >> 16);
}
__device__ __forceinline__ float b2f(u16 u){
  union { uint32_t i; float f; } v; v.i = ((uint32_t)u) << 16; return v.f;
}
__device__ __forceinline__ float sigmoidf(float x){ return 1.0f / (1.0f + __expf(-x)); }

// ---- K0: pack allw = concat(w0,w1) rows as bf16 pairs (unchanged from R6).
__global__ __launch_bounds__(256) void k_prep(
    const float* __restrict__ w0, const float* __restrict__ w1,
    uint32_t* __restrict__ wpk){
  int tid = threadIdx.x, blk = blockIdx.x;         // 0..127
  int b = blk >> 6;
  int j = (blk & 63) * 64 + (tid >> 2);
  int part = tid & 3;
  const float* src = (j < 2048) ? (w0 + ((size_t)(b*2048 + j))*64 + part*16)
                                : (w1 + ((size_t)(b*2048 + j - 2048))*64 + part*16);
  uint32_t* dst = wpk + ((size_t)b*4096 + j)*32 + part*8;
  float4 v0 = ((const float4*)src)[0];
  float4 v1 = ((const float4*)src)[1];
  float4 v2 = ((const float4*)src)[2];
  float4 v3 = ((const float4*)src)[3];
  uint4 o0, o1;
  o0.x = (uint32_t)f2b(v0.x) | ((uint32_t)f2b(v0.y) << 16);
  o0.y = (uint32_t)f2b(v0.z) | ((uint32_t)f2b(v0.w) << 16);
  o0.z = (uint32_t)f2b(v1.x) | ((uint32_t)f2b(v1.y) << 16);
  o0.w = (uint32_t)f2b(v1.z) | ((uint32_t)f2b(v1.w) << 16);
  o1.x = (uint32_t)f2b(v2.x) | ((uint32_t)f2b(v2.y) << 16);
  o1.y = (uint32_t)f2b(v2.z) | ((uint32_t)f2b(v2.w) << 16);
  o1.z = (uint32_t)f2b(v3.x) | ((uint32_t)f2b(v3.y) << 16);
  o1.w = (uint32_t)f2b(v3.z) | ((uint32_t)f2b(v3.w) << 16);
  ((uint4*)dst)[0] = o0;
  ((uint4*)dst)[1] = o1;
}

// ---- K1: persistent mask-stream + gather; wem is NOT streamed.
// Big tasks: stream ww only (4KB/chunk), ballot ww!=0, queue-compact; in the
// gather, fetch wem[row][j] as a 4B broadcast alongside each bf16 w-row pair;
// accumulate + degree-count predicated on wem!=0. Dep tasks = R6 verbatim.
__global__ __launch_bounds__(256) void k_bits(
    const float* __restrict__ ww, const float* __restrict__ wem,
    const float* __restrict__ d0, const float* __restrict__ d1,
    const float* __restrict__ wes, const float* __restrict__ wop,
    const uint32_t* __restrict__ wpk,
    const float* __restrict__ nh, const float* __restrict__ Wg, const float* __restrict__ bg,
    const float* __restrict__ Wf, const float* __restrict__ Wupd, const float* __restrict__ Wo,
    u16* __restrict__ psumB, int* __restrict__ pcntB,
    u16* __restrict__ psumD, int* __restrict__ pcntD,
    u64* __restrict__ bitOp, float* __restrict__ ghat,
    uint32_t* __restrict__ pkWf, uint32_t* __restrict__ pkWu, uint32_t* __restrict__ pkWo){
  __shared__ int q[4][288];
  int tid = threadIdx.x, wave = tid >> 6, lane = tid & 63;
  int bid = blockIdx.x;
  if (bid >= 2048){
    if (bid >= 2304){
      int aux = bid - 2304;                        // 0..16
      if (aux == 16){                              // ghat
        if (tid < 128){
          int b = tid >> 6, h = tid & 63;
          float g = bg[h];
          for (int d = 0; d < 64; ++d) g += nh[b*64 + d] * Wg[d*64 + h];
          float ss = g * g;
          #pragma unroll
          for (int o = 32; o > 0; o >>= 1) ss += __shfl_xor(ss, o, 64);
          ghat[b*64 + h] = g / (sqrtf(ss) + 1e-30f);
        }
        return;
      }
      for (int k = tid; k < 1024; k += 256){       // bf16-pair weight packing
        int i = aux*1024 + k;                      // 0..16383
        const float* src; uint32_t* dst; int li;
        if (i < 8192){ src = Wf; dst = pkWf; li = i; }
        else if (i < 14336){ src = Wupd; dst = pkWu; li = i - 8192; }
        else { src = Wo; dst = pkWo; li = i - 14336; }
        int k2 = li >> 6, ln = li & 63;
        dst[li] = (uint32_t)f2b(src[(2*k2)*64 + ln]) | ((uint32_t)f2b(src[(2*k2+1)*64 + ln]) << 16);
      }
      return;
    }
    // wop bits: wes & wop -> bitOp[n][o>>6]
    int w = (bid - 2048)*4 + wave;                 // 0..1023
    int ng0 = w * 8;
    #pragma unroll
    for (int i = 0; i < 8; ++i){
      int n = ng0 + i;
      float vx = wop[(size_t)n*128 + lane];
      float vy = wop[(size_t)n*128 + 64 + lane];
      float e  = wes[n];
      u64 m0 = __ballot((e != 0.f) && (vx != 0.f));
      u64 m1 = __ballot((e != 0.f) && (vy != 0.f));
      if (lane == 0) bitOp[(size_t)n*2]     = m0;
      if (lane == 1) bitOp[(size_t)n*2 + 1] = m1;
    }
    return;
  }
  int wid = bid*4 + wave;
  float4 a0, a1, a2, a3;
#define ISSUE_MASKS(tt) { \
  int t_ = (tt); \
  const float* A_; \
  if (t_ < 32768){ \
    int row_ = t_ >> 2, ch_ = t_ & 3; \
    A_ = ww + (size_t)row_*4096 + ch_*1024; \
  } else { \
    int idx_ = t_ - 32768, rowp_ = idx_ >> 1, ch_ = idx_ & 1; \
    if (rowp_ < 4096) A_ = d0 + (size_t)rowp_*2048 + ch_*1024; \
    else { int rr_ = rowp_ - 4096; A_ = d1 + (size_t)rr_*2048 + ch_*1024; } \
  } \
  const float4* ra_ = (const float4*)A_ + lane; \
  a0 = ra_[0]; a1 = ra_[64]; a2 = ra_[128]; a3 = ra_[192]; }
  ISSUE_MASKS(wid)                                  // task 0 is always big (wid<8192)
  int half = lane >> 5;
  int dcol = lane & 31;
  #pragma unroll 1
  for (int it = 0; it < 6; ++it){
    int t = wid + it*8192;
    bool big = (t < 32768);
    // ---- gather params (wave-uniform)
    const uint32_t* wub;                           // allw pk base + jadd*32 + dcol
    const float* wemRow;                           // wem row base (big only)
    u16* ps; int* pc;
    if (big){
      int row = t >> 2, chunk = t & 3;
      int b = row >> 12;
      wub = wpk + (size_t)b*131072 + (size_t)(chunk*1024)*32 + dcol;
      wemRow = wem + (size_t)row*4096 + chunk*1024;
      ps = psumB + (size_t)t*64; pc = pcntB + t;
    } else {
      int idx = t - 32768, rowp = idx >> 1, chunk = idx & 1;
      int b, jadd = chunk*1024;
      if (rowp < 4096){ b = rowp >> 11; }
      else { int rr = rowp - 4096; b = rr >> 11; jadd += 2048; }   // d1 -> w1 half of allw
      wub = wpk + (size_t)b*131072 + (size_t)jadd*32 + dcol;
      wemRow = wem;                                // unused
      ps = psumD + (size_t)idx*64; pc = pcntD + idx;
    }
    // ---- ballot current mask (single operand) -> 16 words (lanes 0..15)
    u64 myw = 0;
#define B4(i, va) { \
  u64 m0 = __ballot(va.x != 0.f); \
  u64 m1 = __ballot(va.y != 0.f); \
  u64 m2 = __ballot(va.z != 0.f); \
  u64 m3 = __ballot(va.w != 0.f); \
  if (lane == (i)*4 + 0) myw = m0; \
  if (lane == (i)*4 + 1) myw = m1; \
  if (lane == (i)*4 + 2) myw = m2; \
  if (lane == (i)*4 + 3) myw = m3; }
    B4(0, a0) B4(1, a1) B4(2, a2) B4(3, a3)
#undef B4
    // ---- compact nonzero chunk-cols into LDS queue
    int c = __popcll(myw);
    int pre = c;
    #pragma unroll
    for (int off = 1; off < 64; off <<= 1){
      int tt = __shfl_up(pre, off, 64);
      if (lane >= off) pre += tt;
    }
    int total = __shfl(pre, 63, 64);
    int base = pre - c;
    int colhi = (lane >> 2) * 256 + (lane & 3);
    u64 m = myw;
    while (m){
      int p = __builtin_ctzll(m); m &= m - 1;
      q[wave][base++] = colhi + p*4;
    }
    int totP = (total + 31) & ~31;                 // pad to 32 (2 rows x 16 loads)
    if (lane < totP - total) q[wave][total + lane] = 0;
    // ---- issue NEXT task's masks NOW (in flight across the whole gather)
    if (it < 5) ISSUE_MASKS(t + 8192)
    // ---- gather: 16-deep dbuf, 32 rows/batch, no vmcnt(0) drains
    float accE = 0.f, accO = 0.f;
    int nb = totP >> 5;
    uint32_t g0[16], g1[16];
    if (big){
      float m0a[16], m1a[16];
      int vc = 0;
#define GISSB(arr, wma, bi) { int bse = (bi) << 5; \
  _Pragma("unroll") for (int k2 = 0; k2 < 16; ++k2){ \
    int j = q[wave][bse + 2*k2 + half]; \
    arr[k2] = wub[(size_t)j*32]; \
    wma[k2] = wemRow[j]; } }
#define GACCB(arr, wma, bi) { int bse = (bi) << 5; \
  _Pragma("unroll") for (int k2 = 0; k2 < 16; ++k2){ \
    bool v = ((bse + 2*k2 + half) < total) && (wma[k2] != 0.f); \
    uint32_t wv = arr[k2]; \
    accE += v ? b2f((u16)wv) : 0.f; \
    accO += v ? b2f((u16)(wv >> 16)) : 0.f; \
    vc += v ? 1 : 0; } }
      if (nb > 0) GISSB(g0, m0a, 0)
      for (int bi = 0; bi < nb; bi += 2){
        if (bi + 1 < nb) GISSB(g1, m1a, bi + 1)
        GACCB(g0, m0a, bi)
        if (bi + 1 < nb){
          if (bi + 2 < nb) GISSB(g0, m0a, bi + 2)
          GACCB(g1, m1a, bi + 1)
        }
      }
#undef GISSB
#undef GACCB
      accE += __shfl_xor(accE, 32, 64);
      accO += __shfl_xor(accO, 32, 64);
      vc   += __shfl_xor(vc, 32, 64);
      if (lane < 32)
        ((uint32_t*)ps)[lane] = (uint32_t)f2b(accE) | ((uint32_t)f2b(accO) << 16);
      if (lane == 0) pc[0] = vc;
    } else {
#define GISS(arr, bi) { int bse = (bi) << 5; \
  _Pragma("unroll") for (int k2 = 0; k2 < 16; ++k2){ \
    int j = q[wave][bse + 2*k2 + half]; \
    arr[k2] = wub[(size_t)j*32]; } }
#define GACC(arr, bi) { int bse = (bi) << 5; \
  _Pragma("unroll") for (int k2 = 0; k2 < 16; ++k2){ \
    bool v = (bse + 2*k2 + half) < total; \
    uint32_t wv = arr[k2]; \
    accE += v ? b2f((u16)wv) : 0.f; \
    accO += v ? b2f((u16)(wv >> 16)) : 0.f; } }
      if (nb > 0) GISS(g0, 0)
      for (int bi = 0; bi < nb; bi += 2){
        if (bi + 1 < nb) GISS(g1, bi + 1)
        GACC(g0, bi)
        if (bi + 1 < nb){
          if (bi + 2 < nb) GISS(g0, bi + 2)
          GACC(g1, bi + 1)
        }
      }
#undef GISS
#undef GACC
      accE += __shfl_xor(accE, 32, 64);
      accO += __shfl_xor(accO, 32, 64);
      if (lane < 32)
        ((uint32_t*)ps)[lane] = (uint32_t)f2b(accE) | ((uint32_t)f2b(accO) << 16);
      if (lane == 0) pc[0] = total;
    }
  }
#undef ISSUE_MASKS
}

// ---- K2: FUSED fin+update (unchanged from R6).
__global__ __launch_bounds__(256, 2) void k_mid(
    const u16* __restrict__ psumB, const int* __restrict__ pcntB,
    const u16* __restrict__ psumD, const int* __restrict__ pcntD,
    const float* __restrict__ Wwk, const float* __restrict__ bwk,
    const float* __restrict__ Wws, const float* __restrict__ bws,
    const float* __restrict__ w0, const float* __restrict__ w1,
    const float* __restrict__ gw, const float* __restrict__ ghat,
    const uint32_t* __restrict__ pkWf, const uint32_t* __restrict__ pkWu,
    const uint32_t* __restrict__ pkWo,
    const float* __restrict__ bf, const float* __restrict__ bupd, const float* __restrict__ bo,
    float* __restrict__ out, float* __restrict__ WUo){
  __shared__ uint32_t ldsU[16384];    // 64 KB union: {sWk,sWs} then {pWf,pWu,pWo}
  __shared__ float xsh[4][256];       // 4 KB
  int tid = threadIdx.x, lane = tid & 63, wave = tid >> 6;
  float* sWk = (float*)ldsU;          // [4096]
  float* sWs = (float*)ldsU + 4096;   // [4096]
  for (int i = tid; i < 1024; i += 256){
    ((float4*)sWk)[i] = ((const float4*)Wwk)[i];
    ((float4*)sWs)[i] = ((const float4*)Wws)[i];
  }
  __syncthreads();
  float bwkL = bwk[lane], bwsL = bws[lane];
  float wk[4], wsv[4], aw[4], wgv[4];
  #pragma unroll
  for (int t = 0; t < 4; ++t){
    int row = blockIdx.x*4 + wave + t*2048;        // global row 0..8191
    int b = row >> 12, n = row & 4095;
    float S = b2f(psumB[((size_t)row*4 + 0)*64 + lane]) + b2f(psumB[((size_t)row*4 + 1)*64 + lane])
            + b2f(psumB[((size_t)row*4 + 2)*64 + lane]) + b2f(psumB[((size_t)row*4 + 3)*64 + lane]);
    int T = pcntB[row*4] + pcntB[row*4 + 1] + pcntB[row*4 + 2] + pcntB[row*4 + 3];
    float y = (float)T * bwkL;
    #pragma unroll 8
    for (int d = 0; d < 64; ++d) y += __shfl(S, d, 64) * sWk[d*64 + lane];
    float ss = y * y;
    #pragma unroll
    for (int o = 32; o > 0; o >>= 1) ss += __shfl_xor(ss, o, 64);
    wk[t] = y / (sqrtf(ss) + 1e-30f);
    int rp = (n < 2048) ? (b*2048 + n) : (4096 + b*2048 + (n - 2048));
    float S2 = b2f(psumD[((size_t)rp*2 + 0)*64 + lane]) + b2f(psumD[((size_t)rp*2 + 1)*64 + lane]);
    int T2 = pcntD[rp*2] + pcntD[rp*2 + 1];
    float y2 = (float)T2 * bwsL;
    #pragma unroll 8
    for (int d = 0; d < 64; ++d) y2 += __shfl(S2, d, 64) * sWs[d*64 + lane];
    float ss2 = y2 * y2;
    #pragma unroll
    for (int o = 32; o > 0; o >>= 1) ss2 += __shfl_xor(ss2, o, 64);
    wsv[t] = y2 / (sqrtf(ss2) + 1e-30f);
    aw[t] = (n < 2048) ? w0[((size_t)(b*2048 + n))*64 + lane]
                       : w1[((size_t)(b*2048 + n - 2048))*64 + lane];
    wgv[t] = (gw[b*4096 + n] != 0.f) ? ghat[b*64 + lane] : 0.f;
  }
  __syncthreads();                     // all waves done reading sWk/sWs
  uint32_t* pWf = ldsU;                // [8192]  32 KB
  uint32_t* pWu = ldsU + 8192;         // [6144]  24 KB
  uint32_t* pWo = ldsU + 14336;        // [2048]   8 KB
  for (int i = tid; i < 2048; i += 256) ((uint4*)pWf)[i] = ((const uint4*)pkWf)[i];
  for (int i = tid; i < 1536; i += 256) ((uint4*)pWu)[i] = ((const uint4*)pkWu)[i];
  for (int i = tid; i < 512;  i += 256) ((uint4*)pWo)[i] = ((const uint4*)pkWo)[i];
  __syncthreads();
  float bff = bf[lane], bup = bupd[lane], boo = bo[lane];
  #pragma unroll
  for (int t = 0; t < 4; ++t){
    int row = blockIdx.x*4 + wave + t*2048;
    int b = row >> 12, n = row & 4095;
    xsh[wave][lane] = aw[t]; xsh[wave][64 + lane] = wgv[t];
    xsh[wave][128 + lane] = wk[t]; xsh[wave][192 + lane] = wsv[t];
    float f = bff, u = bup;
    #pragma unroll 8
    for (int k2 = 0; k2 < 32; ++k2){
      float2 xv = *(const float2*)&xsh[wave][2*k2];
      uint32_t wf = pWf[k2*64 + lane];
      f += xv.x * b2f((u16)wf) + xv.y * b2f((u16)(wf >> 16));
    }
    #pragma unroll 8
    for (int k2 = 32; k2 < 128; ++k2){
      float2 xv = *(const float2*)&xsh[wave][2*k2];
      uint32_t wf = pWf[k2*64 + lane];
      uint32_t wu = pWu[(k2 - 32)*64 + lane];
      f += xv.x * b2f((u16)wf) + xv.y * b2f((u16)(wf >> 16));
      u += xv.x * b2f((u16)wu) + xv.y * b2f((u16)(wu >> 16));
    }
    f = sigmoidf(f);
    u = fmaxf(u, 0.f);
    float wu = fmaxf(f, 0.2f) * aw[t] + (1.f - f) * u;
    out[((size_t)b*4224 + n)*64 + lane] = wu;
    float o = boo;
    #pragma unroll 8
    for (int k2 = 0; k2 < 32; ++k2){
      uint32_t wo2 = pWo[k2*64 + lane];
      o += __shfl(wu, 2*k2, 64) * b2f((u16)wo2) + __shfl(wu, 2*k2 + 1, 64) * b2f((u16)(wo2 >> 16));
    }
    WUo[(size_t)row*64 + lane] = o;
  }
}

// ---- K3: fused op aggregation + epilogue (unchanged). One block per (b,o).
__global__ __launch_bounds__(256) void k_opfin(
    const u64* __restrict__ bitOp, const float* __restrict__ WUo,
    const float* __restrict__ opE,
    const float* __restrict__ Wf2, const float* __restrict__ bf2,
    const float* __restrict__ Wout, const float* __restrict__ bout,
    float* __restrict__ out){
  __shared__ float sW2[8192];   // 32 KB
  __shared__ float sWo[4096];   // 16 KB
  __shared__ int q[4][96];
  __shared__ float sacc[4][64];
  __shared__ int scnt[4];
  __shared__ float xsh[128];
  int tid = threadIdx.x, lane = tid & 63, wave = tid >> 6;
  for (int i = tid; i < 2048; i += 256) ((float4*)sW2)[i] = ((const float4*)Wf2)[i];
  for (int i = tid; i < 1024; i += 256) ((float4*)sWo)[i] = ((const float4*)Wout)[i];
  int rowIdx = blockIdx.x;                      // b*128 + o
  int b = rowIdx >> 7, o = rowIdx & 127;
  int wrd = o >> 6, bit = o & 63;
  const u64* bp = bitOp + (size_t)b*8192 + (size_t)wave*2048 + wrd;
  u64 lt = (1ULL << lane) - 1ULL;
  u64 vv[16];
  #pragma unroll
  for (int it = 0; it < 16; ++it) vv[it] = bp[(size_t)(it*64 + lane)*2];
  int cnt = 0;
  #pragma unroll
  for (int it = 0; it < 16; ++it){
    bool nz = (vv[it] >> bit) & 1ULL;
    u64 m = __ballot(nz);
    if (nz) q[wave][cnt + (int)__popcll(m & lt)] = wave*1024 + it*64 + lane;
    cnt += (int)__popcll(m);
  }
  const float* Xb = WUo + (size_t)b*4096*64 + lane;
  float acc = 0.f;
  int i = 0;
  for (; i + 8 <= cnt; i += 8){
    int4 c0 = *(const int4*)&q[wave][i];
    int4 c1 = *(const int4*)&q[wave][i + 4];
    float v0 = Xb[(size_t)c0.x*64], v1 = Xb[(size_t)c0.y*64];
    float v2 = Xb[(size_t)c0.z*64], v3 = Xb[(size_t)c0.w*64];
    float v4 = Xb[(size_t)c1.x*64], v5 = Xb[(size_t)c1.y*64];
    float v6 = Xb[(size_t)c1.z*64], v7 = Xb[(size_t)c1.w*64];
    acc += ((v0 + v1) + (v2 + v3)) + ((v4 + v5) + (v6 + v7));
  }
  for (; i < cnt; ++i) acc += Xb[(size_t)q[wave][i]*64];
  sacc[wave][lane] = acc;
  if (lane == 0) scnt[wave] = cnt;
  __syncthreads();
  if (wave == 0){
    float t = sacc[0][lane] + sacc[1][lane] + sacc[2][lane] + sacc[3][lane];
    float deg = (float)(scnt[0] + scnt[1] + scnt[2] + scnt[3]);
    float wo = t / (deg + 1e-30f);
    float e  = opE[(size_t)rowIdx*64 + lane];
    xsh[lane] = e; xsh[64 + lane] = wo;
    float f = bf2[lane], u = bout[lane];
    #pragma unroll 8
    for (int k = 0; k < 128; ++k) f += xsh[k] * sW2[k*64 + lane];
    #pragma unroll 8
    for (int d = 0; d < 64; ++d)  u += xsh[64 + d] * sWo[d*64 + lane];
    f = sigmoidf(f);
    u = fmaxf(u, 0.f);
    float res = fmaxf(f, 0.2f) * e + (1.f - f) * u;
    out[((size_t)b*4224 + 4096 + o)*64 + lane] = res;
  }
}

extern "C" void kernel_launch(void* const* d_in, const int* in_sizes, int n_in,
                              void* d_out, int out_size, void* d_ws, size_t ws_size,
                              hipStream_t stream){
  const float* w0   = (const float*)d_in[0];
  const float* w1   = (const float*)d_in[1];
  const float* nh   = (const float*)d_in[2];
  const float* opE  = (const float*)d_in[3];
  const float* wes  = (const float*)d_in[4];
  const float* wem  = (const float*)d_in[5];
  const float* wop  = (const float*)d_in[6];
  const float* ww   = (const float*)d_in[7];
  const float* d0   = (const float*)d_in[8];
  const float* d1   = (const float*)d_in[9];
  const float* gw   = (const float*)d_in[10];
  const float* Wg   = (const float*)d_in[11];
  const float* bg   = (const float*)d_in[12];
  const float* Wwk  = (const float*)d_in[13];
  const float* bwk  = (const float*)d_in[14];
  const float* Wws  = (const float*)d_in[15];
  const float* bws  = (const float*)d_in[16];
  const float* Wo   = (const float*)d_in[17];
  const float* bo   = (const float*)d_in[18];
  const float* Wupd = (const float*)d_in[19];
  const float* bupd = (const float*)d_in[20];
  const float* Wf   = (const float*)d_in[21];
  const float* bf   = (const float*)d_in[22];
  const float* Wf2  = (const float*)d_in[23];
  const float* bf2  = (const float*)d_in[24];
  const float* Wout = (const float*)d_in[25];
  const float* bout = (const float*)d_in[26];

  float* ws    = (float*)d_ws;
  float* ghat  = ws;                             // 128
  uint32_t* pkWf = (uint32_t*)(ws + 128);        // 8192 u32
  uint32_t* pkWu = (uint32_t*)(ws + 8320);       // 6144 u32
  uint32_t* pkWo = (uint32_t*)(ws + 14464);      // 2048 u32
  u64*  bitOp  = (u64*)(ws + 16512);             // 16384 u64 (32768 f32)
  u16*  psumB  = (u16*)(ws + 49280);             // 32768 chunks x 64 u16 (1048576 f32)
  int*  pcntB  = (int*)(ws + 1097856);           // 32768 int
  u16*  psumD  = (u16*)(ws + 1130624);           // 16384 chunks x 64 u16 (524288 f32)
  int*  pcntD  = (int*)(ws + 1654912);           // 16384 int
  float* WUo   = ws + 2195584;                   // 524288 f32
  uint32_t* wpk = (uint32_t*)(ws + 2719872);     // 262144 u32 -> ws end 2982016 f32
  float* out   = (float*)d_out;

  k_prep<<<128, 256, 0, stream>>>(w0, w1, wpk);
  k_bits<<<2321, 256, 0, stream>>>(ww, wem, d0, d1, wes, wop, wpk,
                                   nh, Wg, bg, Wf, Wupd, Wo,
                                   psumB, pcntB, psumD, pcntD,
                                   bitOp, ghat, pkWf, pkWu, pkWo);
  k_mid<<<512, 256, 0, stream>>>(psumB, pcntB, psumD, pcntD,
                                 Wwk, bwk, Wws, bws, w0, w1, gw, ghat,
                                 pkWf, pkWu, pkWo, bf, bupd, bo, out, WUo);
  k_opfin<<<256, 256, 0, stream>>>(bitOp, WUo, opE, Wf2, bf2, Wout, bout, out);
}

// Round 8
// 409.096 us; speedup vs baseline: 1.2607x; 1.0057x over previous
//
#include <hip/hip_runtime.h>
#include <cstdint>

typedef unsigned short u16;
typedef unsigned long long u64;

__device__ __forceinline__ u16 f2b(float f){
  union { float f; uint32_t i; } v; v.f = f;
  uint32_t r = v.i + 0x7FFFu + ((v.i >> 16) & 1u);   // RNE
  return (u16)(r >> 16);
}
__device__ __forceinline__ float b2f(u16 u){
  union { uint32_t i; float f; } v; v.i = ((uint32_t)u) << 16; return v.f;
}
__device__ __forceinline__ float sigmoidf(float x){ return 1.0f / (1.0f + __expf(-x)); }

// ---- K0: pack allw = concat(w0,w1) rows as bf16 pairs (unchanged).
__global__ __launch_bounds__(256) void k_prep(
    const float* __restrict__ w0, const float* __restrict__ w1,
    uint32_t* __restrict__ wpk){
  int tid = threadIdx.x, blk = blockIdx.x;         // 0..127
  int b = blk >> 6;
  int j = (blk & 63) * 64 + (tid >> 2);
  int part = tid & 3;
  const float* src = (j < 2048) ? (w0 + ((size_t)(b*2048 + j))*64 + part*16)
                                : (w1 + ((size_t)(b*2048 + j - 2048))*64 + part*16);
  uint32_t* dst = wpk + ((size_t)b*4096 + j)*32 + part*8;
  float4 v0 = ((const float4*)src)[0];
  float4 v1 = ((const float4*)src)[1];
  float4 v2 = ((const float4*)src)[2];
  float4 v3 = ((const float4*)src)[3];
  uint4 o0, o1;
  o0.x = (uint32_t)f2b(v0.x) | ((uint32_t)f2b(v0.y) << 16);
  o0.y = (uint32_t)f2b(v0.z) | ((uint32_t)f2b(v0.w) << 16);
  o0.z = (uint32_t)f2b(v1.x) | ((uint32_t)f2b(v1.y) << 16);
  o0.w = (uint32_t)f2b(v1.z) | ((uint32_t)f2b(v1.w) << 16);
  o1.x = (uint32_t)f2b(v2.x) | ((uint32_t)f2b(v2.y) << 16);
  o1.y = (uint32_t)f2b(v2.z) | ((uint32_t)f2b(v2.w) << 16);
  o1.z = (uint32_t)f2b(v3.x) | ((uint32_t)f2b(v3.y) << 16);
  o1.w = (uint32_t)f2b(v3.z) | ((uint32_t)f2b(v3.w) << 16);
  ((uint4*)dst)[0] = o0;
  ((uint4*)dst)[1] = o1;
}

// ---- K1: FULL-ROW tasks. Each wave: 1 big row (4096 cols, 64 ballot words)
// then 1 dep row (2048 cols, 32 words). wem not streamed (gathered per-hit,
// multiply-by-mask since wem in {0,1}); dep masks prefetched before the big
// gather; per-row psum/pcnt written once (no partial combine downstream).
__global__ __launch_bounds__(256) void k_bits(
    const float* __restrict__ ww, const float* __restrict__ wem,
    const float* __restrict__ d0, const float* __restrict__ d1,
    const float* __restrict__ wes, const float* __restrict__ wop,
    const uint32_t* __restrict__ wpk,
    const float* __restrict__ nh, const float* __restrict__ Wg, const float* __restrict__ bg,
    const float* __restrict__ Wf, const float* __restrict__ Wupd, const float* __restrict__ Wo,
    u16* __restrict__ psumB, int* __restrict__ pcntB,
    u16* __restrict__ psumD, int* __restrict__ pcntD,
    u64* __restrict__ bitOp, float* __restrict__ ghat,
    uint32_t* __restrict__ pkWf, uint32_t* __restrict__ pkWu, uint32_t* __restrict__ pkWo){
  __shared__ int q[4][288];
  int tid = threadIdx.x, wave = tid >> 6, lane = tid & 63;
  int bid = blockIdx.x;
  if (bid >= 2048){
    if (bid >= 2304){
      int aux = bid - 2304;                        // 0..16
      if (aux == 16){                              // ghat
        if (tid < 128){
          int b = tid >> 6, h = tid & 63;
          float g = bg[h];
          for (int d = 0; d < 64; ++d) g += nh[b*64 + d] * Wg[d*64 + h];
          float ss = g * g;
          #pragma unroll
          for (int o = 32; o > 0; o >>= 1) ss += __shfl_xor(ss, o, 64);
          ghat[b*64 + h] = g / (sqrtf(ss) + 1e-30f);
        }
        return;
      }
      for (int k = tid; k < 1024; k += 256){       // bf16-pair weight packing
        int i = aux*1024 + k;                      // 0..16383
        const float* src; uint32_t* dst; int li;
        if (i < 8192){ src = Wf; dst = pkWf; li = i; }
        else if (i < 14336){ src = Wupd; dst = pkWu; li = i - 8192; }
        else { src = Wo; dst = pkWo; li = i - 14336; }
        int k2 = li >> 6, ln = li & 63;
        dst[li] = (uint32_t)f2b(src[(2*k2)*64 + ln]) | ((uint32_t)f2b(src[(2*k2+1)*64 + ln]) << 16);
      }
      return;
    }
    // wop bits: wes & wop -> bitOp[n][o>>6]
    int w = (bid - 2048)*4 + wave;                 // 0..1023
    int ng0 = w * 8;
    #pragma unroll
    for (int i = 0; i < 8; ++i){
      int n = ng0 + i;
      float vx = wop[(size_t)n*128 + lane];
      float vy = wop[(size_t)n*128 + 64 + lane];
      float e  = wes[n];
      u64 m0 = __ballot((e != 0.f) && (vx != 0.f));
      u64 m1 = __ballot((e != 0.f) && (vy != 0.f));
      if (lane == 0) bitOp[(size_t)n*2]     = m0;
      if (lane == 1) bitOp[(size_t)n*2 + 1] = m1;
    }
    return;
  }
  int wid = bid*4 + wave;                          // 0..8191 = big row = dep row id
  int half = lane >> 5, dcol = lane & 31;
  int colhi = (lane >> 2) * 256 + (lane & 3);
  float4 a[8];
  u64 myw = 0;
  // ---- BIG row: stream ww row (16 float4/lane in 2 half-groups) -> 64 words
  const float4* r0 = (const float4*)(ww + (size_t)wid*4096) + lane;
  #pragma unroll
  for (int i = 0; i < 8; ++i) a[i] = r0[i*64];
#define BAL8(wb) { \
  _Pragma("unroll") for (int i = 0; i < 8; ++i){ \
    u64 m0 = __ballot(a[i].x != 0.f); \
    u64 m1 = __ballot(a[i].y != 0.f); \
    u64 m2 = __ballot(a[i].z != 0.f); \
    u64 m3 = __ballot(a[i].w != 0.f); \
    if (lane == (wb) + i*4 + 0) myw = m0; \
    if (lane == (wb) + i*4 + 1) myw = m1; \
    if (lane == (wb) + i*4 + 2) myw = m2; \
    if (lane == (wb) + i*4 + 3) myw = m3; } }
  BAL8(0)
  #pragma unroll
  for (int i = 0; i < 8; ++i) a[i] = r0[512 + i*64];
  BAL8(32)
  // ---- compact -> queue
  int c = __popcll(myw);
  int pre = c;
  #pragma unroll
  for (int off = 1; off < 64; off <<= 1){
    int tt = __shfl_up(pre, off, 64);
    if (lane >= off) pre += tt;
  }
  int total = __shfl(pre, 63, 64);
  int base = pre - c;
  u64 m = myw;
  while (m){
    int p = __builtin_ctzll(m); m &= m - 1;
    q[wave][base++] = colhi + p*4;
  }
  int totP = (total + 31) & ~31;
  if (lane < totP - total) q[wave][total + lane] = 0;
  // ---- prefetch DEP row masks (in flight across the big gather)
  const float* depBase; int jadd, bdep;
  if (wid < 4096){ depBase = d0 + (size_t)wid*2048; jadd = 0; bdep = wid >> 11; }
  else { int rr = wid - 4096; depBase = d1 + (size_t)rr*2048; jadd = 2048; bdep = rr >> 11; }
  {
    const float4* r2 = (const float4*)depBase + lane;
    #pragma unroll
    for (int i = 0; i < 8; ++i) a[i] = r2[i*64];
  }
  // ---- BIG gather: 16-deep dbuf pair-gather + wem per-hit (multiply-by-mask)
  {
    int b = wid >> 12;
    const uint32_t* wub = wpk + (size_t)b*131072 + dcol;
    const float* wemRow = wem + (size_t)wid*4096;
    float accE = 0.f, accO = 0.f, vcF = 0.f;
    int nb = totP >> 5;
    uint32_t g0[16], g1[16];
    float m0a[16], m1a[16];
#define GISSB(arr, wma, bi) { int bse = (bi) << 5; \
  _Pragma("unroll") for (int k2 = 0; k2 < 16; ++k2){ \
    int j = q[wave][bse + 2*k2 + half]; \
    arr[k2] = wub[(size_t)j*32]; \
    wma[k2] = wemRow[j]; } }
#define GACCB(arr, wma, bi) { int bse = (bi) << 5; \
  _Pragma("unroll") for (int k2 = 0; k2 < 16; ++k2){ \
    float sel = ((bse + 2*k2 + half) < total) ? wma[k2] : 0.f; \
    uint32_t wv = arr[k2]; \
    accE += sel * b2f((u16)wv); \
    accO += sel * b2f((u16)(wv >> 16)); \
    vcF += sel; } }
    if (nb > 0) GISSB(g0, m0a, 0)
    for (int bi = 0; bi < nb; bi += 2){
      if (bi + 1 < nb) GISSB(g1, m1a, bi + 1)
      GACCB(g0, m0a, bi)
      if (bi + 1 < nb){
        if (bi + 2 < nb) GISSB(g0, m0a, bi + 2)
        GACCB(g1, m1a, bi + 1)
      }
    }
#undef GISSB
#undef GACCB
    accE += __shfl_xor(accE, 32, 64);
    accO += __shfl_xor(accO, 32, 64);
    vcF  += __shfl_xor(vcF, 32, 64);
    if (lane < 32)
      ((uint32_t*)(psumB + (size_t)wid*64))[lane] =
        (uint32_t)f2b(accE) | ((uint32_t)f2b(accO) << 16);
    if (lane == 0) pcntB[wid] = (int)(vcF + 0.5f);
  }
  // ---- DEP row: ballot prefetched masks (32 words) -> queue -> gather
  myw = 0;
  BAL8(0)
#undef BAL8
  c = __popcll(myw);
  pre = c;
  #pragma unroll
  for (int off = 1; off < 64; off <<= 1){
    int tt = __shfl_up(pre, off, 64);
    if (lane >= off) pre += tt;
  }
  total = __shfl(pre, 63, 64);
  base = pre - c;
  m = myw;
  while (m){
    int p = __builtin_ctzll(m); m &= m - 1;
    q[wave][base++] = colhi + p*4;
  }
  totP = (total + 31) & ~31;
  if (lane < totP - total) q[wave][total + lane] = 0;
  {
    const uint32_t* wub = wpk + (size_t)bdep*131072 + (size_t)jadd*32 + dcol;
    float accE = 0.f, accO = 0.f;
    int nb = totP >> 5;
    uint32_t g0[16], g1[16];
#define GISS(arr, bi) { int bse = (bi) << 5; \
  _Pragma("unroll") for (int k2 = 0; k2 < 16; ++k2){ \
    int j = q[wave][bse + 2*k2 + half]; \
    arr[k2] = wub[(size_t)j*32]; } }
#define GACC(arr, bi) { int bse = (bi) << 5; \
  _Pragma("unroll") for (int k2 = 0; k2 < 16; ++k2){ \
    bool v = (bse + 2*k2 + half) < total; \
    uint32_t wv = arr[k2]; \
    accE += v ? b2f((u16)wv) : 0.f; \
    accO += v ? b2f((u16)(wv >> 16)) : 0.f; } }
    if (nb > 0) GISS(g0, 0)
    for (int bi = 0; bi < nb; bi += 2){
      if (bi + 1 < nb) GISS(g1, bi + 1)
      GACC(g0, bi)
      if (bi + 1 < nb){
        if (bi + 2 < nb) GISS(g0, bi + 2)
        GACC(g1, bi + 1)
      }
    }
#undef GISS
#undef GACC
    accE += __shfl_xor(accE, 32, 64);
    accO += __shfl_xor(accO, 32, 64);
    if (lane < 32)
      ((uint32_t*)(psumD + (size_t)wid*64))[lane] =
        (uint32_t)f2b(accE) | ((uint32_t)f2b(accO) << 16);
    if (lane == 0) pcntD[wid] = total;
  }
}

// ---- K2: FUSED fin+update; psum now per-row (single read, no combine).
__global__ __launch_bounds__(256, 2) void k_mid(
    const u16* __restrict__ psumB, const int* __restrict__ pcntB,
    const u16* __restrict__ psumD, const int* __restrict__ pcntD,
    const float* __restrict__ Wwk, const float* __restrict__ bwk,
    const float* __restrict__ Wws, const float* __restrict__ bws,
    const float* __restrict__ w0, const float* __restrict__ w1,
    const float* __restrict__ gw, const float* __restrict__ ghat,
    const uint32_t* __restrict__ pkWf, const uint32_t* __restrict__ pkWu,
    const uint32_t* __restrict__ pkWo,
    const float* __restrict__ bf, const float* __restrict__ bupd, const float* __restrict__ bo,
    float* __restrict__ out, float* __restrict__ WUo){
  __shared__ uint32_t ldsU[16384];    // 64 KB union: {sWk,sWs} then {pWf,pWu,pWo}
  __shared__ float xsh[4][256];       // 4 KB
  int tid = threadIdx.x, lane = tid & 63, wave = tid >> 6;
  float* sWk = (float*)ldsU;          // [4096]
  float* sWs = (float*)ldsU + 4096;   // [4096]
  for (int i = tid; i < 1024; i += 256){
    ((float4*)sWk)[i] = ((const float4*)Wwk)[i];
    ((float4*)sWs)[i] = ((const float4*)Wws)[i];
  }
  __syncthreads();
  float bwkL = bwk[lane], bwsL = bws[lane];
  float wk[4], wsv[4], aw[4], wgv[4];
  #pragma unroll
  for (int t = 0; t < 4; ++t){
    int row = blockIdx.x*4 + wave + t*2048;        // global row 0..8191
    int b = row >> 12, n = row & 4095;
    float S = b2f(psumB[(size_t)row*64 + lane]);
    int T = pcntB[row];
    float y = (float)T * bwkL;
    #pragma unroll 8
    for (int d = 0; d < 64; ++d) y += __shfl(S, d, 64) * sWk[d*64 + lane];
    float ss = y * y;
    #pragma unroll
    for (int o = 32; o > 0; o >>= 1) ss += __shfl_xor(ss, o, 64);
    wk[t] = y / (sqrtf(ss) + 1e-30f);
    int rp = (n < 2048) ? (b*2048 + n) : (4096 + b*2048 + (n - 2048));
    float S2 = b2f(psumD[(size_t)rp*64 + lane]);
    int T2 = pcntD[rp];
    float y2 = (float)T2 * bwsL;
    #pragma unroll 8
    for (int d = 0; d < 64; ++d) y2 += __shfl(S2, d, 64) * sWs[d*64 + lane];
    float ss2 = y2 * y2;
    #pragma unroll
    for (int o = 32; o > 0; o >>= 1) ss2 += __shfl_xor(ss2, o, 64);
    wsv[t] = y2 / (sqrtf(ss2) + 1e-30f);
    aw[t] = (n < 2048) ? w0[((size_t)(b*2048 + n))*64 + lane]
                       : w1[((size_t)(b*2048 + n - 2048))*64 + lane];
    wgv[t] = (gw[b*4096 + n] != 0.f) ? ghat[b*64 + lane] : 0.f;
  }
  __syncthreads();                     // all waves done reading sWk/sWs
  uint32_t* pWf = ldsU;                // [8192]  32 KB
  uint32_t* pWu = ldsU + 8192;         // [6144]  24 KB
  uint32_t* pWo = ldsU + 14336;        // [2048]   8 KB
  for (int i = tid; i < 2048; i += 256) ((uint4*)pWf)[i] = ((const uint4*)pkWf)[i];
  for (int i = tid; i < 1536; i += 256) ((uint4*)pWu)[i] = ((const uint4*)pkWu)[i];
  for (int i = tid; i < 512;  i += 256) ((uint4*)pWo)[i] = ((const uint4*)pkWo)[i];
  __syncthreads();
  float bff = bf[lane], bup = bupd[lane], boo = bo[lane];
  #pragma unroll
  for (int t = 0; t < 4; ++t){
    int row = blockIdx.x*4 + wave + t*2048;
    int b = row >> 12, n = row & 4095;
    xsh[wave][lane] = aw[t]; xsh[wave][64 + lane] = wgv[t];
    xsh[wave][128 + lane] = wk[t]; xsh[wave][192 + lane] = wsv[t];
    float f = bff, u = bup;
    #pragma unroll 8
    for (int k2 = 0; k2 < 32; ++k2){
      float2 xv = *(const float2*)&xsh[wave][2*k2];
      uint32_t wf = pWf[k2*64 + lane];
      f += xv.x * b2f((u16)wf) + xv.y * b2f((u16)(wf >> 16));
    }
    #pragma unroll 8
    for (int k2 = 32; k2 < 128; ++k2){
      float2 xv = *(const float2*)&xsh[wave][2*k2];
      uint32_t wf = pWf[k2*64 + lane];
      uint32_t wu = pWu[(k2 - 32)*64 + lane];
      f += xv.x * b2f((u16)wf) + xv.y * b2f((u16)(wf >> 16));
      u += xv.x * b2f((u16)wu) + xv.y * b2f((u16)(wu >> 16));
    }
    f = sigmoidf(f);
    u = fmaxf(u, 0.f);
    float wu = fmaxf(f, 0.2f) * aw[t] + (1.f - f) * u;
    out[((size_t)b*4224 + n)*64 + lane] = wu;
    float o = boo;
    #pragma unroll 8
    for (int k2 = 0; k2 < 32; ++k2){
      uint32_t wo2 = pWo[k2*64 + lane];
      o += __shfl(wu, 2*k2, 64) * b2f((u16)wo2) + __shfl(wu, 2*k2 + 1, 64) * b2f((u16)(wo2 >> 16));
    }
    WUo[(size_t)row*64 + lane] = o;
  }
}

// ---- K3: fused op aggregation + epilogue (unchanged). One block per (b,o).
__global__ __launch_bounds__(256) void k_opfin(
    const u64* __restrict__ bitOp, const float* __restrict__ WUo,
    const float* __restrict__ opE,
    const float* __restrict__ Wf2, const float* __restrict__ bf2,
    const float* __restrict__ Wout, const float* __restrict__ bout,
    float* __restrict__ out){
  __shared__ float sW2[8192];   // 32 KB
  __shared__ float sWo[4096];   // 16 KB
  __shared__ int q[4][96];
  __shared__ float sacc[4][64];
  __shared__ int scnt[4];
  __shared__ float xsh[128];
  int tid = threadIdx.x, lane = tid & 63, wave = tid >> 6;
  for (int i = tid; i < 2048; i += 256) ((float4*)sW2)[i] = ((const float4*)Wf2)[i];
  for (int i = tid; i < 1024; i += 256) ((float4*)sWo)[i] = ((const float4*)Wout)[i];
  int rowIdx = blockIdx.x;                      // b*128 + o
  int b = rowIdx >> 7, o = rowIdx & 127;
  int wrd = o >> 6, bit = o & 63;
  const u64* bp = bitOp + (size_t)b*8192 + (size_t)wave*2048 + wrd;
  u64 lt = (1ULL << lane) - 1ULL;
  u64 vv[16];
  #pragma unroll
  for (int it = 0; it < 16; ++it) vv[it] = bp[(size_t)(it*64 + lane)*2];
  int cnt = 0;
  #pragma unroll
  for (int it = 0; it < 16; ++it){
    bool nz = (vv[it] >> bit) & 1ULL;
    u64 m = __ballot(nz);
    if (nz) q[wave][cnt + (int)__popcll(m & lt)] = wave*1024 + it*64 + lane;
    cnt += (int)__popcll(m);
  }
  const float* Xb = WUo + (size_t)b*4096*64 + lane;
  float acc = 0.f;
  int i = 0;
  for (; i + 8 <= cnt; i += 8){
    int4 c0 = *(const int4*)&q[wave][i];
    int4 c1 = *(const int4*)&q[wave][i + 4];
    float v0 = Xb[(size_t)c0.x*64], v1 = Xb[(size_t)c0.y*64];
    float v2 = Xb[(size_t)c0.z*64], v3 = Xb[(size_t)c0.w*64];
    float v4 = Xb[(size_t)c1.x*64], v5 = Xb[(size_t)c1.y*64];
    float v6 = Xb[(size_t)c1.z*64], v7 = Xb[(size_t)c1.w*64];
    acc += ((v0 + v1) + (v2 + v3)) + ((v4 + v5) + (v6 + v7));
  }
  for (; i < cnt; ++i) acc += Xb[(size_t)q[wave][i]*64];
  sacc[wave][lane] = acc;
  if (lane == 0) scnt[wave] = cnt;
  __syncthreads();
  if (wave == 0){
    float t = sacc[0][lane] + sacc[1][lane] + sacc[2][lane] + sacc[3][lane];
    float deg = (float)(scnt[0] + scnt[1] + scnt[2] + scnt[3]);
    float wo = t / (deg + 1e-30f);
    float e  = opE[(size_t)rowIdx*64 + lane];
    xsh[lane] = e; xsh[64 + lane] = wo;
    float f = bf2[lane], u = bout[lane];
    #pragma unroll 8
    for (int k = 0; k < 128; ++k) f += xsh[k] * sW2[k*64 + lane];
    #pragma unroll 8
    for (int d = 0; d < 64; ++d)  u += xsh[64 + d] * sWo[d*64 + lane];
    f = sigmoidf(f);
    u = fmaxf(u, 0.f);
    float res = fmaxf(f, 0.2f) * e + (1.f - f) * u;
    out[((size_t)b*4224 + 4096 + o)*64 + lane] = res;
  }
}

extern "C" void kernel_launch(void* const* d_in, const int* in_sizes, int n_in,
                              void* d_out, int out_size, void* d_ws, size_t ws_size,
                              hipStream_t stream){
  const float* w0   = (const float*)d_in[0];
  const float* w1   = (const float*)d_in[1];
  const float* nh   = (const float*)d_in[2];
  const float* opE  = (const float*)d_in[3];
  const float* wes  = (const float*)d_in[4];
  const float* wem  = (const float*)d_in[5];
  const float* wop  = (const float*)d_in[6];
  const float* ww   = (const float*)d_in[7];
  const float* d0   = (const float*)d_in[8];
  const float* d1   = (const float*)d_in[9];
  const float* gw   = (const float*)d_in[10];
  const float* Wg   = (const float*)d_in[11];
  const float* bg   = (const float*)d_in[12];
  const float* Wwk  = (const float*)d_in[13];
  const float* bwk  = (const float*)d_in[14];
  const float* Wws  = (const float*)d_in[15];
  const float* bws  = (const float*)d_in[16];
  const float* Wo   = (const float*)d_in[17];
  const float* bo   = (const float*)d_in[18];
  const float* Wupd = (const float*)d_in[19];
  const float* bupd = (const float*)d_in[20];
  const float* Wf   = (const float*)d_in[21];
  const float* bf   = (const float*)d_in[22];
  const float* Wf2  = (const float*)d_in[23];
  const float* bf2  = (const float*)d_in[24];
  const float* Wout = (const float*)d_in[25];
  const float* bout = (const float*)d_in[26];

  float* ws    = (float*)d_ws;
  float* ghat  = ws;                             // 128
  uint32_t* pkWf = (uint32_t*)(ws + 128);        // 8192 u32
  uint32_t* pkWu = (uint32_t*)(ws + 8320);       // 6144 u32
  uint32_t* pkWo = (uint32_t*)(ws + 14464);      // 2048 u32
  u64*  bitOp  = (u64*)(ws + 16512);             // 16384 u64 (32768 f32)
  u16*  psumB  = (u16*)(ws + 49280);             // 8192 rows x 64 u16 (262144 f32)
  int*  pcntB  = (int*)(ws + 311424);            // 8192 int
  u16*  psumD  = (u16*)(ws + 319616);            // 8192 rows x 64 u16 (262144 f32)
  int*  pcntD  = (int*)(ws + 581760);            // 8192 int
  float* WUo   = ws + 589952;                    // 524288 f32
  uint32_t* wpk = (uint32_t*)(ws + 1114240);     // 262144 u32 -> ws end 1376384 f32
  float* out   = (float*)d_out;

  k_prep<<<128, 256, 0, stream>>>(w0, w1, wpk);
  k_bits<<<2321, 256, 0, stream>>>(ww, wem, d0, d1, wes, wop, wpk,
                                   nh, Wg, bg, Wf, Wupd, Wo,
                                   psumB, pcntB, psumD, pcntD,
                                   bitOp, ghat, pkWf, pkWu, pkWo);
  k_mid<<<512, 256, 0, stream>>>(psumB, pcntB, psumD, pcntD,
                                 Wwk, bwk, Wws, bws, w0, w1, gw, ghat,
                                 pkWf, pkWu, pkWo, bf, bupd, bo, out, WUo);
  k_opfin<<<256, 256, 0, stream>>>(bitOp, WUo, opE, Wf2, bf2, Wout, bout, out);
}